// Round 1
// 350.624 us; speedup vs baseline: 1.0370x; 1.0370x over previous
//
#include <hip/hip_runtime.h>

#define DD 128

typedef __attribute__((ext_vector_type(8))) short short8;
typedef __attribute__((ext_vector_type(4))) float f32x4;
typedef __attribute__((ext_vector_type(4))) int i32x4;

__device__ __forceinline__ unsigned short f2bf(float f) {
    union { float f; unsigned int i; } c; c.f = f;
    unsigned int x = c.i;
    return (unsigned short)((x + 0x7fffu + ((x >> 16) & 1u)) >> 16);
}
__device__ __forceinline__ float bfu(unsigned short u) {
    union { unsigned int i; float f; } c; c.i = ((unsigned int)u) << 16; return c.f;
}
// Index accessor robust to int32 vs int64 (little-endian, nonneg values < 2^31)
__device__ __forceinline__ int idx_at(const int* p, int e, int is64) {
    return is64 ? p[2 * e] : p[e];
}
// Per-block int64 detection: int64 => odd 32-bit words (high halves) all zero.
__device__ __forceinline__ int block_is64(const int* dst, int nE, int* s_flag) {
    if (threadIdx.x == 0) *s_flag = 0;
    __syncthreads();
    int w = 2 * (int)threadIdx.x + 1;
    if (threadIdx.x < 128 && w < nE && dst[w] != 0) atomicOr(s_flag, 1);
    __syncthreads();
    return !*s_flag;
}

// ---- prep: one kernel, roles by blockIdx:
// [0, nConvH)      : h fp32 -> hB bf16 (2048 elems/block)
// [+nConvH)        : prevh fp32 -> bf16 into d_out slot second half (row*512+256)
// [+48)            : 3 weights transposed+converted into Wt
// [+nEmbB)         : emb fp32 -> embB bf16
// [+nHistB)        : in-degree histogram (deg pre-zeroed by memsetAsync)
__global__ __launch_bounds__(256) void prep_k(
    const float* __restrict__ h, const float* __restrict__ prevh,
    const float* __restrict__ W0, const float* __restrict__ W1,
    const float* __restrict__ W2, const float* __restrict__ emb,
    const int* __restrict__ dst,
    unsigned short* __restrict__ hB, char* __restrict__ aggP,
    unsigned short* __restrict__ embB, unsigned short* __restrict__ Wt,
    int* __restrict__ deg, int nN, int nEmbEl, int nE) {
    int tid = threadIdx.x;
    int bid = blockIdx.x;
    int totalH = nN * DD;
    int nConvH = (totalH + 2047) / 2048;
    if (bid < 2 * nConvH) {
        int which = bid >= nConvH;
        int base = (which ? bid - nConvH : bid) * 2048 + tid * 8;
        const float* S = which ? prevh : h;
        if (base + 8 <= totalH) {
            f32x4 x0 = *(const f32x4*)(S + base);
            f32x4 x1 = *(const f32x4*)(S + base + 4);
            short8 p;
            #pragma unroll
            for (int j = 0; j < 4; ++j) {
                p[j]     = (short)f2bf(x0[j]);
                p[4 + j] = (short)f2bf(x1[j]);
            }
            if (which) {
                int row = base >> 7, col = base & 127;
                *(short8*)(aggP + (size_t)row * 512 + 256 + col * 2) = p;
            } else {
                *(short8*)(hB + base) = p;
            }
        } else {
            for (int j = base; j < totalH; ++j) {
                unsigned short v = f2bf(S[j]);
                if (which) *(unsigned short*)(aggP + (size_t)(j >> 7) * 512 + 256 +
                                              (j & 127) * 2) = v;
                else hB[j] = v;
            }
        }
        return;
    }
    bid -= 2 * nConvH;
    if (bid < 48) {
        const float* Ws[3] = {W0, W1, W2};
        int w = bid >> 4, chunk = bid & 15;
        unsigned short* T = Wt + w * (DD * DD);
        #pragma unroll
        for (int i = 0; i < 4; ++i) {
            int t = chunk * 1024 + i * 256 + tid;
            int n = t >> 7, k = t & 127;
            T[t] = f2bf(Ws[w][k * DD + n]);
        }
        return;
    }
    bid -= 48;
    int nEmbB = (nEmbEl + 2047) / 2048;
    if (bid < nEmbB) {
        int base = bid * 2048 + tid * 8;
        if (base + 8 <= nEmbEl) {
            f32x4 x0 = *(const f32x4*)(emb + base);
            f32x4 x1 = *(const f32x4*)(emb + base + 4);
            short8 p;
            #pragma unroll
            for (int j = 0; j < 4; ++j) {
                p[j]     = (short)f2bf(x0[j]);
                p[4 + j] = (short)f2bf(x1[j]);
            }
            *(short8*)(embB + base) = p;
        } else {
            for (int j = base; j < nEmbEl; ++j) embB[j] = f2bf(emb[j]);
        }
        return;
    }
    bid -= nEmbB;
    // histogram role
    __shared__ int s_flag;
    int is64 = block_is64(dst, nE, &s_flag);
    int e = bid * 256 + tid;
    if (e < nE) atomicAdd(deg + idx_at(dst, e, is64), 1);
}

// ---- exclusive scan, step 1
__global__ __launch_bounds__(1024) void scan1_k(const int* deg, int* off, int* bsum,
                                                int nN) {
    __shared__ int s[1024];
    int t = threadIdx.x, i = blockIdx.x * 1024 + t;
    int v = (i < nN) ? deg[i] : 0;
    s[t] = v;
    __syncthreads();
    for (int d = 1; d < 1024; d <<= 1) {
        int x = (t >= d) ? s[t - d] : 0;
        __syncthreads();
        s[t] += x;
        __syncthreads();
    }
    if (i < nN) off[i] = s[t] - v;
    if (t == 1023) bsum[blockIdx.x] = s[1023];
}

// ---- steps 2+3 merged
__global__ __launch_bounds__(1024) void scan23_k(const int* bsum, int* off,
                                                 int* cursor, int nN, int nB) {
    __shared__ int s[1024];
    int t = threadIdx.x;
    s[t] = (t < nB) ? bsum[t] : 0;
    __syncthreads();
    for (int d = 1; d < 1024; d <<= 1) {
        int x = (t >= d) ? s[t - d] : 0;
        __syncthreads();
        s[t] += x;
        __syncthreads();
    }
    int base = (blockIdx.x == 0) ? 0 : s[blockIdx.x - 1];
    int i = blockIdx.x * 1024 + t;
    if (i < nN) {
        int o = off[i] + base;
        off[i] = o;
        cursor[i] = o;
    }
}

// ---- counting sort: packed edge word = src | (etype<<17); bucketed by dst
__global__ __launch_bounds__(256) void sort_k(const int* src, const int* dst,
                                              const int* et, int nE,
                                              int* cursor, unsigned int* edges) {
    __shared__ int s_flag;
    int is64 = block_is64(dst, nE, &s_flag);
    int e = blockIdx.x * 256 + threadIdx.x;
    if (e >= nE) return;
    int d = idx_at(dst, e, is64);
    int pos = atomicAdd(cursor + d, 1);
    edges[pos] = (unsigned int)idx_at(src, e, is64) |
                 ((unsigned int)idx_at(et, e, is64) << 17);
}

// ---- CSR gather, all-bf16: agg[v] = norm[v] * sum (hB[src]+embB[etype]);
// 16 lanes per edge; 8 edges per iteration (two 4-edge rounds, loads issued
// before accumulation for MLP). Packed bf16 into first 256B of d_out slot.
__global__ __launch_bounds__(256) void gather_k(
    const unsigned short* __restrict__ hB, const unsigned short* __restrict__ embB,
    const unsigned int* __restrict__ edges, const int* __restrict__ off,
    const int* __restrict__ deg, const float* __restrict__ normv,
    char* __restrict__ aggP, int nN) {
    int lane = threadIdx.x & 63;
    int v = blockIdx.x * 4 + (threadIdx.x >> 6);
    if (v >= nN) return;
    int slot = lane >> 4, l16 = lane & 15;
    int b = off[v], n = deg[v];
    float a[8] = {0.f, 0.f, 0.f, 0.f, 0.f, 0.f, 0.f, 0.f};
    for (int base = 0; base < n; base += 8) {
        int m0 = base + slot, m1 = base + 4 + slot;
        bool v0 = m0 < n, v1 = m1 < n;
        unsigned int w0 = 0, w1 = 0;
        if (v0) w0 = edges[b + m0];
        if (v1) w1 = edges[b + m1];
        short8 hv0, rv0, hv1, rv1;
        if (v0) {
            hv0 = *(const short8*)(hB + (size_t)(w0 & 0x1FFFFu) * DD + l16 * 8);
            rv0 = *(const short8*)(embB + (size_t)(w0 >> 17) * DD + l16 * 8);
        }
        if (v1) {
            hv1 = *(const short8*)(hB + (size_t)(w1 & 0x1FFFFu) * DD + l16 * 8);
            rv1 = *(const short8*)(embB + (size_t)(w1 >> 17) * DD + l16 * 8);
        }
        if (v0) {
            #pragma unroll
            for (int j = 0; j < 8; ++j)
                a[j] += bfu((unsigned short)hv0[j]) + bfu((unsigned short)rv0[j]);
        }
        if (v1) {
            #pragma unroll
            for (int j = 0; j < 8; ++j)
                a[j] += bfu((unsigned short)hv1[j]) + bfu((unsigned short)rv1[j]);
        }
    }
    #pragma unroll
    for (int j = 0; j < 8; ++j) {
        a[j] += __shfl_xor(a[j], 16);
        a[j] += __shfl_xor(a[j], 32);
    }
    if (slot == 0) {
        float nm = normv[v];
        short8 p;
        #pragma unroll
        for (int j = 0; j < 8; ++j) p[j] = (short)f2bf(a[j] * nm);
        *(short8*)(aggP + (size_t)v * 512 + l16 * 16) = p;
    }
}

// ---- fused 3-GEMM + epilogue (64-node tile).
// Block = 4 waves, wave wv -> cols [32wv,32wv+32). accM = agg@Wn + h@Wl;
// accG = pB@Ws. The old accP = pB@I identity-GEMM is gone: the epilogue
// reads prevh fp32 straight from the INPUT buffer (no aliasing with the
// d_out slots being overwritten, so it is safe after the barrier, and it
// costs zero registers live across the barrier). AGPR footprint drops
// 96 -> 64 so arch-reg total ~150 -> 3 blocks/CU instead of 2.
// deg==0 rows patched exactly by fix_k afterwards.
__global__ __launch_bounds__(256, 3) void fused_k(
    const unsigned short* __restrict__ hB,
    const float* __restrict__ prevh,
    const float* __restrict__ bias,
    const char* aggP,                    // = d_out: [0,256)=agg bf16, [256,512)=prevh bf16
    const unsigned short* __restrict__ Wt,
    float* out, int nN) {
    const int lane = threadIdx.x & 63;
    const int wv = threadIdx.x >> 6;
    const int q = lane >> 4, cl = lane & 15;
    const int node_base = blockIdx.x * 64;
    const int ncb = wv * 32;

    f32x4 accM[4][2], accG[4][2];
    #pragma unroll
    for (int mt = 0; mt < 4; ++mt)
        #pragma unroll
        for (int nt = 0; nt < 2; ++nt) {
            accM[mt][nt] = (f32x4){0.f, 0.f, 0.f, 0.f};
            accG[mt][nt] = (f32x4){0.f, 0.f, 0.f, 0.f};
        }

    // pass 1: accM = agg@Wn + hB@Wl
    #pragma unroll
    for (int g = 0; g < 2; ++g) {
        const unsigned short* Wg = Wt + g * (DD * DD);
        #pragma unroll
        for (int ks = 0; ks < 4; ++ks) {
            short8 bfr[2];
            #pragma unroll
            for (int nt = 0; nt < 2; ++nt)
                bfr[nt] = *(const short8*)(Wg + (ncb + nt * 16 + cl) * DD +
                                           ks * 32 + q * 8);
            #pragma unroll
            for (int mt = 0; mt < 4; ++mt) {
                int row = node_base + mt * 16 + cl;
                if (row > nN - 1) row = nN - 1;
                short8 a = (g == 0)
                    ? *(const short8*)(aggP + (size_t)row * 512 + ks * 64 + q * 16)
                    : *(const short8*)(hB + (size_t)row * DD + ks * 32 + q * 8);
                #pragma unroll
                for (int nt = 0; nt < 2; ++nt)
                    accM[mt][nt] = __builtin_amdgcn_mfma_f32_16x16x32_bf16(
                        a, bfr[nt], accM[mt][nt], 0, 0, 0);
            }
        }
    }
    // pass 2: accG = pB@Ws
    #pragma unroll
    for (int ks = 0; ks < 4; ++ks) {
        short8 bS[2];
        #pragma unroll
        for (int nt = 0; nt < 2; ++nt) {
            int n = (ncb + nt * 16 + cl) * DD + ks * 32 + q * 8;
            bS[nt] = *(const short8*)(Wt + 2 * DD * DD + n);
        }
        #pragma unroll
        for (int mt = 0; mt < 4; ++mt) {
            int row = node_base + mt * 16 + cl;
            if (row > nN - 1) row = nN - 1;
            short8 a = *(const short8*)(aggP + (size_t)row * 512 + 256 +
                                        ks * 64 + q * 16);
            #pragma unroll
            for (int nt = 0; nt < 2; ++nt)
                accG[mt][nt] = __builtin_amdgcn_mfma_f32_16x16x32_bf16(
                    a, bS[nt], accG[mt][nt], 0, 0, 0);
        }
    }

    float b0 = bias[ncb + cl], b1 = bias[ncb + 16 + cl];

    __syncthreads();   // all slot reads (all waves) done before epilogue writes

    // C/D layout: col = lane&15, row = quad*4 + reg
    #pragma unroll
    for (int mt = 0; mt < 4; ++mt) {
        #pragma unroll
        for (int r = 0; r < 4; ++r) {
            int node = node_base + mt * 16 + q * 4 + r;
            if (node >= nN) continue;
            const float* pr = prevh + (size_t)node * DD;
            #pragma unroll
            for (int nt = 0; nt < 2; ++nt) {
                int col = ncb + nt * 16 + cl;
                float pv = pr[col];
                float sg = 1.0f / (1.0f + __expf(-(accG[mt][nt][r] + (nt ? b1 : b0))));
                float o  = sg * accM[mt][nt][r] + (1.0f - sg) * pv;
                out[(size_t)node * DD + col] = (o > 0.f ? o : 0.f);
            }
        }
    }
}

// ---- patch deg==0 nodes exactly (fp32)
__global__ __launch_bounds__(256) void fix_k(
    const float* __restrict__ h, const float* __restrict__ prevh,
    const float* __restrict__ bias, const float* __restrict__ We,
    const float* __restrict__ Wsk, const int* __restrict__ deg,
    float* __restrict__ out, int nN, int chunk) {
    __shared__ int list[256];
    __shared__ int cnt;
    __shared__ float hrow[DD], prow[DD], res[2][DD];
    int tid = threadIdx.x;
    int base = blockIdx.x * chunk;
    for (int c = base; c < base + chunk && c < nN; c += 256) {
        if (tid == 0) cnt = 0;
        __syncthreads();
        int v = c + tid;
        if (v < nN && v < base + chunk && deg[v] == 0)
            list[atomicAdd(&cnt, 1)] = v;
        __syncthreads();
        int m = cnt;
        for (int i = 0; i < m; ++i) {
            int node = list[i];
            if (tid < DD) hrow[tid] = h[(size_t)node * DD + tid];
            else prow[tid - DD] = prevh[(size_t)node * DD + tid - DD];
            __syncthreads();
            int col = tid & (DD - 1);
            int half = tid >> 7;
            const float* W = half ? Wsk : We;
            const float* x = half ? prow : hrow;
            float s = 0.f;
            for (int k = 0; k < DD; ++k) s += x[k] * W[k * DD + col];
            res[half][col] = s;
            __syncthreads();
            if (tid < DD) {
                float sg = 1.0f / (1.0f + __expf(-(res[1][col] + bias[col])));
                float o  = sg * res[0][col] + (1.0f - sg) * prow[col];
                out[(size_t)node * DD + col] = (o > 0.f ? o : 0.f);
            }
            __syncthreads();
        }
        __syncthreads();
    }
}

extern "C" void kernel_launch(void* const* d_in, const int* in_sizes, int n_in,
                              void* d_out, int out_size, void* d_ws, size_t ws_size,
                              hipStream_t stream) {
    const float* h     = (const float*)d_in[0];
    const float* prevh = (const float*)d_in[1];
    const float* emb   = (const float*)d_in[2];
    const float* normv = (const float*)d_in[3];
    const float* Wn    = (const float*)d_in[4];
    const float* Wl    = (const float*)d_in[5];
    const float* We    = (const float*)d_in[6];
    const float* Wsk   = (const float*)d_in[7];
    const float* bias  = (const float*)d_in[8];
    const int* src   = (const int*)d_in[9];
    const int* dst   = (const int*)d_in[10];
    const int* etype = (const int*)d_in[11];

    int nN = in_sizes[3];       // norm is [N,1]
    int nE = in_sizes[9];
    int nEmbEl = in_sizes[2];   // NUM_RELS * 128

    // ws: Wt 96KB (Wn,Wl,Wsk) | embB | deg off cursor bsum | edges u32 | hB
    char* w = (char*)d_ws;
    size_t o = 0;
    unsigned short* Wt = (unsigned short*)(w + o);  o += 3 * DD * DD * 2;
    unsigned short* embB = (unsigned short*)(w + o); o += ((size_t)nEmbEl * 2 + 255) & ~(size_t)255;
    int* deg    = (int*)(w + o);  o += ((size_t)nN * 4 + 15) & ~(size_t)15;
    int* offA   = (int*)(w + o);  o += ((size_t)nN * 4 + 15) & ~(size_t)15;
    int* cursor = (int*)(w + o);  o += ((size_t)nN * 4 + 15) & ~(size_t)15;
    int* bsum   = (int*)(w + o);  o += 4096;
    unsigned int* edges = (unsigned int*)(w + o); o += ((size_t)nE * 4 + 15) & ~(size_t)15;
    unsigned short* hB = (unsigned short*)(w + o);

    int nConvH = (nN * DD + 2047) / 2048;
    int nEmbB  = (nEmbEl + 2047) / 2048;
    int nHistB = (nE + 255) / 256;
    int nB = (nN + 1023) / 1024;

    hipMemsetAsync(deg, 0, (size_t)nN * sizeof(int), stream);
    prep_k<<<2 * nConvH + 48 + nEmbB + nHistB, 256, 0, stream>>>(
        h, prevh, Wn, Wl, Wsk, emb, dst, hB, (char*)d_out, embB, Wt, deg,
        nN, nEmbEl, nE);
    scan1_k<<<nB, 1024, 0, stream>>>(deg, offA, bsum, nN);
    scan23_k<<<nB, 1024, 0, stream>>>(bsum, offA, cursor, nN, nB);
    sort_k<<<(nE + 255) / 256, 256, 0, stream>>>(src, dst, etype, nE, cursor, edges);
    gather_k<<<(nN + 3) / 4, 256, 0, stream>>>(hB, embB, edges, offA, deg, normv,
                                               (char*)d_out, nN);
    fused_k<<<(nN + 63) / 64, 256, 0, stream>>>(hB, prevh, bias, (const char*)d_out,
                                                Wt, (float*)d_out, nN);
    int fgrid = 256;
    int chunk = ((nN + fgrid * 256 - 1) / (fgrid * 256)) * 256;
    fix_k<<<fgrid, 256, 0, stream>>>(h, prevh, bias, We, Wsk, deg, (float*)d_out,
                                     nN, chunk);
    (void)ws_size; (void)n_in; (void)out_size;
}

// Round 2
// 322.219 us; speedup vs baseline: 1.1285x; 1.0882x over previous
//
#include <hip/hip_runtime.h>

#define DD 128

typedef __attribute__((ext_vector_type(8))) short short8;
typedef __attribute__((ext_vector_type(4))) float f32x4;
typedef __attribute__((ext_vector_type(4))) int i32x4;

__device__ __forceinline__ unsigned short f2bf(float f) {
    union { float f; unsigned int i; } c; c.f = f;
    unsigned int x = c.i;
    return (unsigned short)((x + 0x7fffu + ((x >> 16) & 1u)) >> 16);
}
__device__ __forceinline__ float bfu(unsigned short u) {
    union { unsigned int i; float f; } c; c.i = ((unsigned int)u) << 16; return c.f;
}
// async 16B global -> LDS (dest is wave-uniform base + lane*16)
__device__ __forceinline__ void gload_lds16(const void* g, void* l) {
    __builtin_amdgcn_global_load_lds(
        (const __attribute__((address_space(1))) unsigned int*)g,
        (__attribute__((address_space(3))) unsigned int*)l, 16, 0, 0);
}
// Index accessor robust to int32 vs int64 (little-endian, nonneg values < 2^31)
__device__ __forceinline__ int idx_at(const int* p, int e, int is64) {
    return is64 ? p[2 * e] : p[e];
}
// Per-block int64 detection: int64 => odd 32-bit words (high halves) all zero.
__device__ __forceinline__ int block_is64(const int* dst, int nE, int* s_flag) {
    if (threadIdx.x == 0) *s_flag = 0;
    __syncthreads();
    int w = 2 * (int)threadIdx.x + 1;
    if (threadIdx.x < 128 && w < nE && dst[w] != 0) atomicOr(s_flag, 1);
    __syncthreads();
    return !*s_flag;
}

// ---- prep: one kernel, roles by blockIdx:
// [0, nConvH)      : h fp32 -> hB bf16 (2048 elems/block)
// [+nConvH)        : prevh fp32 -> bf16 into d_out slot second half (row*512+256)
// [+48)            : 3 weights transposed+converted into Wt
// [+nEmbB)         : emb fp32 -> embB bf16
// [+nHistB)        : in-degree histogram (deg pre-zeroed by memsetAsync)
__global__ __launch_bounds__(256) void prep_k(
    const float* __restrict__ h, const float* __restrict__ prevh,
    const float* __restrict__ W0, const float* __restrict__ W1,
    const float* __restrict__ W2, const float* __restrict__ emb,
    const int* __restrict__ dst,
    unsigned short* __restrict__ hB, char* __restrict__ aggP,
    unsigned short* __restrict__ embB, unsigned short* __restrict__ Wt,
    int* __restrict__ deg, int nN, int nEmbEl, int nE) {
    int tid = threadIdx.x;
    int bid = blockIdx.x;
    int totalH = nN * DD;
    int nConvH = (totalH + 2047) / 2048;
    if (bid < 2 * nConvH) {
        int which = bid >= nConvH;
        int base = (which ? bid - nConvH : bid) * 2048 + tid * 8;
        const float* S = which ? prevh : h;
        if (base + 8 <= totalH) {
            f32x4 x0 = *(const f32x4*)(S + base);
            f32x4 x1 = *(const f32x4*)(S + base + 4);
            short8 p;
            #pragma unroll
            for (int j = 0; j < 4; ++j) {
                p[j]     = (short)f2bf(x0[j]);
                p[4 + j] = (short)f2bf(x1[j]);
            }
            if (which) {
                int row = base >> 7, col = base & 127;
                *(short8*)(aggP + (size_t)row * 512 + 256 + col * 2) = p;
            } else {
                *(short8*)(hB + base) = p;
            }
        } else {
            for (int j = base; j < totalH; ++j) {
                unsigned short v = f2bf(S[j]);
                if (which) *(unsigned short*)(aggP + (size_t)(j >> 7) * 512 + 256 +
                                              (j & 127) * 2) = v;
                else hB[j] = v;
            }
        }
        return;
    }
    bid -= 2 * nConvH;
    if (bid < 48) {
        const float* Ws[3] = {W0, W1, W2};
        int w = bid >> 4, chunk = bid & 15;
        unsigned short* T = Wt + w * (DD * DD);
        #pragma unroll
        for (int i = 0; i < 4; ++i) {
            int t = chunk * 1024 + i * 256 + tid;
            int n = t >> 7, k = t & 127;
            T[t] = f2bf(Ws[w][k * DD + n]);
        }
        return;
    }
    bid -= 48;
    int nEmbB = (nEmbEl + 2047) / 2048;
    if (bid < nEmbB) {
        int base = bid * 2048 + tid * 8;
        if (base + 8 <= nEmbEl) {
            f32x4 x0 = *(const f32x4*)(emb + base);
            f32x4 x1 = *(const f32x4*)(emb + base + 4);
            short8 p;
            #pragma unroll
            for (int j = 0; j < 4; ++j) {
                p[j]     = (short)f2bf(x0[j]);
                p[4 + j] = (short)f2bf(x1[j]);
            }
            *(short8*)(embB + base) = p;
        } else {
            for (int j = base; j < nEmbEl; ++j) embB[j] = f2bf(emb[j]);
        }
        return;
    }
    bid -= nEmbB;
    // histogram role
    __shared__ int s_flag;
    int is64 = block_is64(dst, nE, &s_flag);
    int e = bid * 256 + tid;
    if (e < nE) atomicAdd(deg + idx_at(dst, e, is64), 1);
}

// ---- exclusive scan, step 1
__global__ __launch_bounds__(1024) void scan1_k(const int* deg, int* off, int* bsum,
                                                int nN) {
    __shared__ int s[1024];
    int t = threadIdx.x, i = blockIdx.x * 1024 + t;
    int v = (i < nN) ? deg[i] : 0;
    s[t] = v;
    __syncthreads();
    for (int d = 1; d < 1024; d <<= 1) {
        int x = (t >= d) ? s[t - d] : 0;
        __syncthreads();
        s[t] += x;
        __syncthreads();
    }
    if (i < nN) off[i] = s[t] - v;
    if (t == 1023) bsum[blockIdx.x] = s[1023];
}

// ---- steps 2+3 merged
__global__ __launch_bounds__(1024) void scan23_k(const int* bsum, int* off,
                                                 int* cursor, int nN, int nB) {
    __shared__ int s[1024];
    int t = threadIdx.x;
    s[t] = (t < nB) ? bsum[t] : 0;
    __syncthreads();
    for (int d = 1; d < 1024; d <<= 1) {
        int x = (t >= d) ? s[t - d] : 0;
        __syncthreads();
        s[t] += x;
        __syncthreads();
    }
    int base = (blockIdx.x == 0) ? 0 : s[blockIdx.x - 1];
    int i = blockIdx.x * 1024 + t;
    if (i < nN) {
        int o = off[i] + base;
        off[i] = o;
        cursor[i] = o;
    }
}

// ---- counting sort: packed edge word = src | (etype<<17); bucketed by dst
__global__ __launch_bounds__(256) void sort_k(const int* src, const int* dst,
                                              const int* et, int nE,
                                              int* cursor, unsigned int* edges) {
    __shared__ int s_flag;
    int is64 = block_is64(dst, nE, &s_flag);
    int e = blockIdx.x * 256 + threadIdx.x;
    if (e >= nE) return;
    int d = idx_at(dst, e, is64);
    int pos = atomicAdd(cursor + d, 1);
    edges[pos] = (unsigned int)idx_at(src, e, is64) |
                 ((unsigned int)idx_at(et, e, is64) << 17);
}

// ---- CSR gather, all-bf16: agg[v] = norm[v] * sum (hB[src]+embB[etype]);
// 16 lanes per edge; 8 edges per iteration. Packed bf16 into first 256B of slot.
__global__ __launch_bounds__(256) void gather_k(
    const unsigned short* __restrict__ hB, const unsigned short* __restrict__ embB,
    const unsigned int* __restrict__ edges, const int* __restrict__ off,
    const int* __restrict__ deg, const float* __restrict__ normv,
    char* __restrict__ aggP, int nN) {
    int lane = threadIdx.x & 63;
    int v = blockIdx.x * 4 + (threadIdx.x >> 6);
    if (v >= nN) return;
    int slot = lane >> 4, l16 = lane & 15;
    int b = off[v], n = deg[v];
    float a[8] = {0.f, 0.f, 0.f, 0.f, 0.f, 0.f, 0.f, 0.f};
    for (int base = 0; base < n; base += 8) {
        int m0 = base + slot, m1 = base + 4 + slot;
        bool v0 = m0 < n, v1 = m1 < n;
        unsigned int w0 = 0, w1 = 0;
        if (v0) w0 = edges[b + m0];
        if (v1) w1 = edges[b + m1];
        short8 hv0, rv0, hv1, rv1;
        if (v0) {
            hv0 = *(const short8*)(hB + (size_t)(w0 & 0x1FFFFu) * DD + l16 * 8);
            rv0 = *(const short8*)(embB + (size_t)(w0 >> 17) * DD + l16 * 8);
        }
        if (v1) {
            hv1 = *(const short8*)(hB + (size_t)(w1 & 0x1FFFFu) * DD + l16 * 8);
            rv1 = *(const short8*)(embB + (size_t)(w1 >> 17) * DD + l16 * 8);
        }
        if (v0) {
            #pragma unroll
            for (int j = 0; j < 8; ++j)
                a[j] += bfu((unsigned short)hv0[j]) + bfu((unsigned short)rv0[j]);
        }
        if (v1) {
            #pragma unroll
            for (int j = 0; j < 8; ++j)
                a[j] += bfu((unsigned short)hv1[j]) + bfu((unsigned short)rv1[j]);
        }
    }
    #pragma unroll
    for (int j = 0; j < 8; ++j) {
        a[j] += __shfl_xor(a[j], 16);
        a[j] += __shfl_xor(a[j], 32);
    }
    if (slot == 0) {
        float nm = normv[v];
        short8 p;
        #pragma unroll
        for (int j = 0; j < 8; ++j) p[j] = (short)f2bf(a[j] * nm);
        *(short8*)(aggP + (size_t)v * 512 + l16 * 16) = p;
    }
}

// ---- fused 3-GEMM + epilogue, LDS-staged (64-node tile, 4 waves).
// Stage agg/hB/prevhB slabs (16KB each) via global_load_lds width=16, source
// chunk pre-swizzled by (chunk ^ (row&15)) so ds_read_b128 fragment reads are
// ~conflict-free (rule #21: linear LDS dest + inverse-swizzled source + same
// XOR on read). One merged K-loop: per (ks,mt) 3 ds_read A-frags, 6 MFMAs.
// All global reads of the aggP slot complete before the single staging
// barrier, so the epilogue (which overwrites the slot with fp32 out) needs no
// second barrier, and prevh comes free from the LDS pB slab (bf16).
// deg==0 rows patched exactly by fix_k afterwards.
__global__ __launch_bounds__(256, 3) void fused_k(
    const unsigned short* __restrict__ hB,
    const float* __restrict__ bias,
    const char* __restrict__ aggP,       // = d_out: [0,256)=agg bf16, [256,512)=prevh bf16
    const unsigned short* __restrict__ Wt,
    float* __restrict__ out, int nN) {
    __shared__ unsigned short lds[3 * 64 * 128];   // AGG | HH | PB slabs, 16KB each
    const int lane = threadIdx.x & 63;
    const int wv = threadIdx.x >> 6;
    const int q = lane >> 4, cl = lane & 15;
    const int node_base = blockIdx.x * 64;
    const int ncb = wv * 32;

    // ---- stage: each wave 4 iters x 3 slabs of async 16B loads (rows wv*4+r0)
    {
        int r0 = lane >> 4;         // 0..3
        int c  = lane & 15;         // chunk 0..15
        #pragma unroll
        for (int it = 0; it < 4; ++it) {
            int r = it * 16 + wv * 4 + r0;
            int row = node_base + r; if (row > nN - 1) row = nN - 1;
            int sw = (c ^ (r & 15)) << 4;           // pre-swizzled source chunk
            const char* gA = aggP + (size_t)row * 512 + sw;
            const char* gP = aggP + (size_t)row * 512 + 256 + sw;
            const char* gH = (const char*)hB + (size_t)row * 256 + sw;
            char* base = (char*)lds + (it * 16 + wv * 4) * 256; // wave-uniform
            gload_lds16(gA, base);
            gload_lds16(gH, base + 16384);
            gload_lds16(gP, base + 32768);
        }
    }
    __syncthreads();   // vmcnt drain + barrier: slabs complete, slot reads done

    const unsigned short* lA = lds;
    const unsigned short* lH = lds + 64 * 128;
    const unsigned short* lP = lds + 2 * 64 * 128;

    f32x4 accM[4][2], accG[4][2];
    #pragma unroll
    for (int mt = 0; mt < 4; ++mt)
        #pragma unroll
        for (int nt = 0; nt < 2; ++nt) {
            accM[mt][nt] = (f32x4){0.f, 0.f, 0.f, 0.f};
            accG[mt][nt] = (f32x4){0.f, 0.f, 0.f, 0.f};
        }

    // ---- merged K-loop: accM = agg@Wn + h@Wl ; accG = pB@Ws
    #pragma unroll
    for (int ks = 0; ks < 4; ++ks) {
        short8 bn[2], bl[2], bs[2];
        #pragma unroll
        for (int nt = 0; nt < 2; ++nt) {
            int n = (ncb + nt * 16 + cl) * DD + ks * 32 + q * 8;
            bn[nt] = *(const short8*)(Wt + n);
            bl[nt] = *(const short8*)(Wt + DD * DD + n);
            bs[nt] = *(const short8*)(Wt + 2 * DD * DD + n);
        }
        int swz = ((ks * 4 + q) ^ cl) << 3;   // r&15 == cl for all mt
        #pragma unroll
        for (int mt = 0; mt < 4; ++mt) {
            int off = (mt * 16 + cl) * 128 + swz;
            short8 aA = *(const short8*)(lA + off);
            short8 aH = *(const short8*)(lH + off);
            short8 aP = *(const short8*)(lP + off);
            #pragma unroll
            for (int nt = 0; nt < 2; ++nt) {
                accM[mt][nt] = __builtin_amdgcn_mfma_f32_16x16x32_bf16(
                    aA, bn[nt], accM[mt][nt], 0, 0, 0);
                accM[mt][nt] = __builtin_amdgcn_mfma_f32_16x16x32_bf16(
                    aH, bl[nt], accM[mt][nt], 0, 0, 0);
                accG[mt][nt] = __builtin_amdgcn_mfma_f32_16x16x32_bf16(
                    aP, bs[nt], accG[mt][nt], 0, 0, 0);
            }
        }
    }

    float b0 = bias[ncb + cl], b1 = bias[ncb + 16 + cl];

    // ---- epilogue: no second barrier needed (all slot reads staged pre-sync).
    // C/D layout: col = lane&15, row = quad*4 + reg. prevh bf16 from LDS pB.
    #pragma unroll
    for (int mt = 0; mt < 4; ++mt) {
        #pragma unroll
        for (int r = 0; r < 4; ++r) {
            int nrow = mt * 16 + q * 4 + r;
            int node = node_base + nrow;
            if (node >= nN) continue;
            #pragma unroll
            for (int nt = 0; nt < 2; ++nt) {
                int col = ncb + nt * 16 + cl;
                float pv = bfu(lP[nrow * 128 +
                                  ((((col >> 3) ^ (nrow & 15)) << 3) | (col & 7))]);
                float sg = 1.0f / (1.0f + __expf(-(accG[mt][nt][r] + (nt ? b1 : b0))));
                float o  = sg * accM[mt][nt][r] + (1.0f - sg) * pv;
                out[(size_t)node * DD + col] = (o > 0.f ? o : 0.f);
            }
        }
    }
}

// ---- patch deg==0 nodes exactly (fp32)
__global__ __launch_bounds__(256) void fix_k(
    const float* __restrict__ h, const float* __restrict__ prevh,
    const float* __restrict__ bias, const float* __restrict__ We,
    const float* __restrict__ Wsk, const int* __restrict__ deg,
    float* __restrict__ out, int nN, int chunk) {
    __shared__ int list[256];
    __shared__ int cnt;
    __shared__ float hrow[DD], prow[DD], res[2][DD];
    int tid = threadIdx.x;
    int base = blockIdx.x * chunk;
    for (int c = base; c < base + chunk && c < nN; c += 256) {
        if (tid == 0) cnt = 0;
        __syncthreads();
        int v = c + tid;
        if (v < nN && v < base + chunk && deg[v] == 0)
            list[atomicAdd(&cnt, 1)] = v;
        __syncthreads();
        int m = cnt;
        for (int i = 0; i < m; ++i) {
            int node = list[i];
            if (tid < DD) hrow[tid] = h[(size_t)node * DD + tid];
            else prow[tid - DD] = prevh[(size_t)node * DD + tid - DD];
            __syncthreads();
            int col = tid & (DD - 1);
            int half = tid >> 7;
            const float* W = half ? Wsk : We;
            const float* x = half ? prow : hrow;
            float s = 0.f;
            for (int k = 0; k < DD; ++k) s += x[k] * W[k * DD + col];
            res[half][col] = s;
            __syncthreads();
            if (tid < DD) {
                float sg = 1.0f / (1.0f + __expf(-(res[1][col] + bias[col])));
                float o  = sg * res[0][col] + (1.0f - sg) * prow[col];
                out[(size_t)node * DD + col] = (o > 0.f ? o : 0.f);
            }
            __syncthreads();
        }
        __syncthreads();
    }
}

extern "C" void kernel_launch(void* const* d_in, const int* in_sizes, int n_in,
                              void* d_out, int out_size, void* d_ws, size_t ws_size,
                              hipStream_t stream) {
    const float* h     = (const float*)d_in[0];
    const float* prevh = (const float*)d_in[1];
    const float* emb   = (const float*)d_in[2];
    const float* normv = (const float*)d_in[3];
    const float* Wn    = (const float*)d_in[4];
    const float* Wl    = (const float*)d_in[5];
    const float* We    = (const float*)d_in[6];
    const float* Wsk   = (const float*)d_in[7];
    const float* bias  = (const float*)d_in[8];
    const int* src   = (const int*)d_in[9];
    const int* dst   = (const int*)d_in[10];
    const int* etype = (const int*)d_in[11];

    int nN = in_sizes[3];       // norm is [N,1]
    int nE = in_sizes[9];
    int nEmbEl = in_sizes[2];   // NUM_RELS * 128

    // ws: Wt 96KB (Wn,Wl,Wsk) | embB | deg off cursor bsum | edges u32 | hB
    char* w = (char*)d_ws;
    size_t o = 0;
    unsigned short* Wt = (unsigned short*)(w + o);  o += 3 * DD * DD * 2;
    unsigned short* embB = (unsigned short*)(w + o); o += ((size_t)nEmbEl * 2 + 255) & ~(size_t)255;
    int* deg    = (int*)(w + o);  o += ((size_t)nN * 4 + 15) & ~(size_t)15;
    int* offA   = (int*)(w + o);  o += ((size_t)nN * 4 + 15) & ~(size_t)15;
    int* cursor = (int*)(w + o);  o += ((size_t)nN * 4 + 15) & ~(size_t)15;
    int* bsum   = (int*)(w + o);  o += 4096;
    unsigned int* edges = (unsigned int*)(w + o); o += ((size_t)nE * 4 + 15) & ~(size_t)15;
    unsigned short* hB = (unsigned short*)(w + o);

    int nConvH = (nN * DD + 2047) / 2048;
    int nEmbB  = (nEmbEl + 2047) / 2048;
    int nHistB = (nE + 255) / 256;
    int nB = (nN + 1023) / 1024;

    hipMemsetAsync(deg, 0, (size_t)nN * sizeof(int), stream);
    prep_k<<<2 * nConvH + 48 + nEmbB + nHistB, 256, 0, stream>>>(
        h, prevh, Wn, Wl, Wsk, emb, dst, hB, (char*)d_out, embB, Wt, deg,
        nN, nEmbEl, nE);
    scan1_k<<<nB, 1024, 0, stream>>>(deg, offA, bsum, nN);
    scan23_k<<<nB, 1024, 0, stream>>>(bsum, offA, cursor, nN, nB);
    sort_k<<<(nE + 255) / 256, 256, 0, stream>>>(src, dst, etype, nE, cursor, edges);
    gather_k<<<(nN + 3) / 4, 256, 0, stream>>>(hB, embB, edges, offA, deg, normv,
                                               (char*)d_out, nN);
    fused_k<<<(nN + 63) / 64, 256, 0, stream>>>(hB, bias, (const char*)d_out, Wt,
                                                (float*)d_out, nN);
    int fgrid = 256;
    int chunk = ((nN + fgrid * 256 - 1) / (fgrid * 256)) * 256;
    fix_k<<<fgrid, 256, 0, stream>>>(h, prevh, bias, We, Wsk, deg, (float*)d_out,
                                     nN, chunk);
    (void)ws_size; (void)n_in; (void)out_size;
}

// Round 3
// 317.967 us; speedup vs baseline: 1.1436x; 1.0134x over previous
//
#include <hip/hip_runtime.h>

#define DD 128

typedef __attribute__((ext_vector_type(8))) short short8;
typedef __attribute__((ext_vector_type(4))) float f32x4;
typedef __attribute__((ext_vector_type(4))) int i32x4;

__device__ __forceinline__ unsigned short f2bf(float f) {
    union { float f; unsigned int i; } c; c.f = f;
    unsigned int x = c.i;
    return (unsigned short)((x + 0x7fffu + ((x >> 16) & 1u)) >> 16);
}
__device__ __forceinline__ float bfu(unsigned short u) {
    union { unsigned int i; float f; } c; c.i = ((unsigned int)u) << 16; return c.f;
}
// async 16B global -> LDS (dest is wave-uniform base + lane*16)
__device__ __forceinline__ void gload_lds16(const void* g, void* l) {
    __builtin_amdgcn_global_load_lds(
        (const __attribute__((address_space(1))) unsigned int*)g,
        (__attribute__((address_space(3))) unsigned int*)l, 16, 0, 0);
}
// Index accessor robust to int32 vs int64 (little-endian, nonneg values < 2^31)
__device__ __forceinline__ int idx_at(const int* p, int e, int is64) {
    return is64 ? p[2 * e] : p[e];
}
// Per-block int64 detection: int64 => odd 32-bit words (high halves) all zero.
__device__ __forceinline__ int block_is64(const int* dst, int nE, int* s_flag) {
    if (threadIdx.x == 0) *s_flag = 0;
    __syncthreads();
    int w = 2 * (int)threadIdx.x + 1;
    if (threadIdx.x < 128 && w < nE && dst[w] != 0) atomicOr(s_flag, 1);
    __syncthreads();
    return !*s_flag;
}

// ---- prep: one kernel, roles by blockIdx (histogram first so the scattered
// atomics overlap the streaming conversion):
// [0, nHistB)   : in-degree histogram, 4 edges/thread (deg pre-zeroed)
// [+nConvH)     : h fp32 -> hB bf16, 8192 elems/block, 8 loads in flight
// [+48)         : 3 weights transposed+converted into Wt
// [+nEmbB)      : emb fp32 -> embB bf16
// (prevh conversion removed: fused_k reg-stages prevh fp32 directly)
__global__ __launch_bounds__(256) void prep_k(
    const float* __restrict__ h,
    const float* __restrict__ W0, const float* __restrict__ W1,
    const float* __restrict__ W2, const float* __restrict__ emb,
    const int* __restrict__ dst,
    unsigned short* __restrict__ hB,
    unsigned short* __restrict__ embB, unsigned short* __restrict__ Wt,
    int* __restrict__ deg, int nN, int nEmbEl, int nE) {
    int tid = threadIdx.x;
    int bid = blockIdx.x;
    int nHistB = (nE + 1023) / 1024;
    if (bid < nHistB) {
        __shared__ int s_flag;
        int is64 = block_is64(dst, nE, &s_flag);
        int e0 = bid * 1024 + tid * 4;
        #pragma unroll
        for (int j = 0; j < 4; ++j) {
            int e = e0 + j;
            if (e < nE) atomicAdd(deg + idx_at(dst, e, is64), 1);
        }
        return;
    }
    bid -= nHistB;
    int totalH = nN * DD;
    int nConvH = (totalH + 8191) / 8192;
    if (bid < nConvH) {
        int base0 = bid * 8192;
        if (base0 + 8192 <= totalH) {
            int base = base0 + tid * 8;
            f32x4 x[4][2];
            #pragma unroll
            for (int i = 0; i < 4; ++i) {
                x[i][0] = *(const f32x4*)(h + base + i * 2048);
                x[i][1] = *(const f32x4*)(h + base + i * 2048 + 4);
            }
            #pragma unroll
            for (int i = 0; i < 4; ++i) {
                short8 p;
                #pragma unroll
                for (int j = 0; j < 4; ++j) {
                    p[j]     = (short)f2bf(x[i][0][j]);
                    p[4 + j] = (short)f2bf(x[i][1][j]);
                }
                *(short8*)(hB + base + i * 2048) = p;
            }
        } else {
            #pragma unroll
            for (int i = 0; i < 4; ++i) {
                int b2 = base0 + i * 2048 + tid * 8;
                if (b2 + 8 <= totalH) {
                    f32x4 x0 = *(const f32x4*)(h + b2);
                    f32x4 x1 = *(const f32x4*)(h + b2 + 4);
                    short8 p;
                    #pragma unroll
                    for (int j = 0; j < 4; ++j) {
                        p[j]     = (short)f2bf(x0[j]);
                        p[4 + j] = (short)f2bf(x1[j]);
                    }
                    *(short8*)(hB + b2) = p;
                } else {
                    for (int j = b2; j < totalH && j < b2 + 8; ++j)
                        hB[j] = f2bf(h[j]);
                }
            }
        }
        return;
    }
    bid -= nConvH;
    if (bid < 48) {
        const float* Ws[3] = {W0, W1, W2};
        int w = bid >> 4, chunk = bid & 15;
        unsigned short* T = Wt + w * (DD * DD);
        #pragma unroll
        for (int i = 0; i < 4; ++i) {
            int t = chunk * 1024 + i * 256 + tid;
            int n = t >> 7, k = t & 127;
            T[t] = f2bf(Ws[w][k * DD + n]);
        }
        return;
    }
    bid -= 48;
    // emb role
    int base = bid * 2048 + tid * 8;
    if (base + 8 <= nEmbEl) {
        f32x4 x0 = *(const f32x4*)(emb + base);
        f32x4 x1 = *(const f32x4*)(emb + base + 4);
        short8 p;
        #pragma unroll
        for (int j = 0; j < 4; ++j) {
            p[j]     = (short)f2bf(x0[j]);
            p[4 + j] = (short)f2bf(x1[j]);
        }
        *(short8*)(embB + base) = p;
    } else {
        for (int j = base; j < nEmbEl; ++j) embB[j] = f2bf(emb[j]);
    }
}

// ---- exclusive scan, step 1
__global__ __launch_bounds__(1024) void scan1_k(const int* deg, int* off, int* bsum,
                                                int nN) {
    __shared__ int s[1024];
    int t = threadIdx.x, i = blockIdx.x * 1024 + t;
    int v = (i < nN) ? deg[i] : 0;
    s[t] = v;
    __syncthreads();
    for (int d = 1; d < 1024; d <<= 1) {
        int x = (t >= d) ? s[t - d] : 0;
        __syncthreads();
        s[t] += x;
        __syncthreads();
    }
    if (i < nN) off[i] = s[t] - v;
    if (t == 1023) bsum[blockIdx.x] = s[1023];
}

// ---- steps 2+3 merged
__global__ __launch_bounds__(1024) void scan23_k(const int* bsum, int* off,
                                                 int* cursor, int nN, int nB) {
    __shared__ int s[1024];
    int t = threadIdx.x;
    s[t] = (t < nB) ? bsum[t] : 0;
    __syncthreads();
    for (int d = 1; d < 1024; d <<= 1) {
        int x = (t >= d) ? s[t - d] : 0;
        __syncthreads();
        s[t] += x;
        __syncthreads();
    }
    int base = (blockIdx.x == 0) ? 0 : s[blockIdx.x - 1];
    int i = blockIdx.x * 1024 + t;
    if (i < nN) {
        int o = off[i] + base;
        off[i] = o;
        cursor[i] = o;
    }
}

// ---- counting sort: packed edge word = src | (etype<<17); bucketed by dst
__global__ __launch_bounds__(256) void sort_k(const int* src, const int* dst,
                                              const int* et, int nE,
                                              int* cursor, unsigned int* edges) {
    __shared__ int s_flag;
    int is64 = block_is64(dst, nE, &s_flag);
    int e = blockIdx.x * 256 + threadIdx.x;
    if (e >= nE) return;
    int d = idx_at(dst, e, is64);
    int pos = atomicAdd(cursor + d, 1);
    edges[pos] = (unsigned int)idx_at(src, e, is64) |
                 ((unsigned int)idx_at(et, e, is64) << 17);
}

// ---- CSR gather, all-bf16: agg[v] = norm[v] * sum (hB[src]+embB[etype]);
// 16 lanes per edge; 8 edges per iteration. Packed bf16 into first 256B of slot.
__global__ __launch_bounds__(256) void gather_k(
    const unsigned short* __restrict__ hB, const unsigned short* __restrict__ embB,
    const unsigned int* __restrict__ edges, const int* __restrict__ off,
    const int* __restrict__ deg, const float* __restrict__ normv,
    char* __restrict__ aggP, int nN) {
    int lane = threadIdx.x & 63;
    int v = blockIdx.x * 4 + (threadIdx.x >> 6);
    if (v >= nN) return;
    int slot = lane >> 4, l16 = lane & 15;
    int b = off[v], n = deg[v];
    float a[8] = {0.f, 0.f, 0.f, 0.f, 0.f, 0.f, 0.f, 0.f};
    for (int base = 0; base < n; base += 8) {
        int m0 = base + slot, m1 = base + 4 + slot;
        bool v0 = m0 < n, v1 = m1 < n;
        unsigned int w0 = 0, w1 = 0;
        if (v0) w0 = edges[b + m0];
        if (v1) w1 = edges[b + m1];
        short8 hv0, rv0, hv1, rv1;
        if (v0) {
            hv0 = *(const short8*)(hB + (size_t)(w0 & 0x1FFFFu) * DD + l16 * 8);
            rv0 = *(const short8*)(embB + (size_t)(w0 >> 17) * DD + l16 * 8);
        }
        if (v1) {
            hv1 = *(const short8*)(hB + (size_t)(w1 & 0x1FFFFu) * DD + l16 * 8);
            rv1 = *(const short8*)(embB + (size_t)(w1 >> 17) * DD + l16 * 8);
        }
        if (v0) {
            #pragma unroll
            for (int j = 0; j < 8; ++j)
                a[j] += bfu((unsigned short)hv0[j]) + bfu((unsigned short)rv0[j]);
        }
        if (v1) {
            #pragma unroll
            for (int j = 0; j < 8; ++j)
                a[j] += bfu((unsigned short)hv1[j]) + bfu((unsigned short)rv1[j]);
        }
    }
    #pragma unroll
    for (int j = 0; j < 8; ++j) {
        a[j] += __shfl_xor(a[j], 16);
        a[j] += __shfl_xor(a[j], 32);
    }
    if (slot == 0) {
        float nm = normv[v];
        short8 p;
        #pragma unroll
        for (int j = 0; j < 8; ++j) p[j] = (short)f2bf(a[j] * nm);
        *(short8*)(aggP + (size_t)v * 512 + l16 * 16) = p;
    }
}

// ---- fused 3-GEMM + epilogue, LDS-staged (64-node tile, 4 waves).
// agg/hB slabs staged via global_load_lds width=16 with pre-swizzled source
// chunk (chunk ^ (row&15)); prevh is reg-staged straight from the fp32 input
// (load f32x4 x8 -> f2bf -> swizzled ds_write_b128), removing the prep-pass
// conversion entirely. All loads drain at the single staging barrier; only
// the agg slab aliases the d_out region this block overwrites (same 512B-slot
// byte range), so no second barrier is needed.
// deg==0 rows patched exactly by fix_k afterwards.
__global__ __launch_bounds__(256, 3) void fused_k(
    const unsigned short* __restrict__ hB,
    const float* __restrict__ prevh,
    const float* __restrict__ bias,
    const char* __restrict__ aggP,       // = d_out: [0,256) of each 512B slot = agg bf16
    const unsigned short* __restrict__ Wt,
    float* __restrict__ out, int nN) {
    __shared__ unsigned short lds[3 * 64 * 128];   // AGG | HH | PB slabs, 16KB each
    const int lane = threadIdx.x & 63;
    const int wv = threadIdx.x >> 6;
    const int q = lane >> 4, cl = lane & 15;
    const int node_base = blockIdx.x * 64;
    const int ncb = wv * 32;

    // ---- stage agg + hB: 4 iters x 2 async 16B loads per lane
    {
        int r0 = lane >> 4;         // 0..3
        int c  = lane & 15;         // chunk 0..15
        #pragma unroll
        for (int it = 0; it < 4; ++it) {
            int r = it * 16 + wv * 4 + r0;
            int row = node_base + r; if (row > nN - 1) row = nN - 1;
            int sw = (c ^ (r & 15)) << 4;           // pre-swizzled source chunk
            char* base = (char*)lds + (it * 16 + wv * 4) * 256; // wave-uniform
            gload_lds16(aggP + (size_t)row * 512 + sw, base);
            gload_lds16((const char*)hB + (size_t)row * 256 + sw, base + 16384);
        }
    }
    // ---- reg-stage prevh fp32 -> bf16 -> PB slab (swizzled ds_write)
    {
        f32x4 t0[4], t1[4];
        #pragma unroll
        for (int it = 0; it < 4; ++it) {
            int pos = it * 512 + lane * 8;      // 0..2047 within this wave's 16 rows
            int row = pos >> 7;                  // 0..15
            int col = pos & 127;
            int node = node_base + wv * 16 + row;
            if (node > nN - 1) node = nN - 1;
            const float* g = prevh + (size_t)node * DD + col;
            t0[it] = *(const f32x4*)g;
            t1[it] = *(const f32x4*)(g + 4);
        }
        #pragma unroll
        for (int it = 0; it < 4; ++it) {
            int pos = it * 512 + lane * 8;
            int r = wv * 16 + (pos >> 7);
            int c = (pos & 127) >> 3;
            short8 p;
            #pragma unroll
            for (int j = 0; j < 4; ++j) {
                p[j]     = (short)f2bf(t0[it][j]);
                p[4 + j] = (short)f2bf(t1[it][j]);
            }
            *(short8*)((char*)lds + 32768 + r * 256 + ((c ^ (r & 15)) << 4)) = p;
        }
    }
    __syncthreads();   // drains global_load_lds + ds_writes; slot reads done

    const unsigned short* lA = lds;
    const unsigned short* lH = lds + 64 * 128;
    const unsigned short* lP = lds + 2 * 64 * 128;

    f32x4 accM[4][2], accG[4][2];
    #pragma unroll
    for (int mt = 0; mt < 4; ++mt)
        #pragma unroll
        for (int nt = 0; nt < 2; ++nt) {
            accM[mt][nt] = (f32x4){0.f, 0.f, 0.f, 0.f};
            accG[mt][nt] = (f32x4){0.f, 0.f, 0.f, 0.f};
        }

    // ---- merged K-loop: accM = agg@Wn + h@Wl ; accG = pB@Ws
    #pragma unroll
    for (int ks = 0; ks < 4; ++ks) {
        short8 bn[2], bl[2], bs[2];
        #pragma unroll
        for (int nt = 0; nt < 2; ++nt) {
            int n = (ncb + nt * 16 + cl) * DD + ks * 32 + q * 8;
            bn[nt] = *(const short8*)(Wt + n);
            bl[nt] = *(const short8*)(Wt + DD * DD + n);
            bs[nt] = *(const short8*)(Wt + 2 * DD * DD + n);
        }
        int swz = ((ks * 4 + q) ^ cl) << 3;   // r&15 == cl for all mt
        #pragma unroll
        for (int mt = 0; mt < 4; ++mt) {
            int off = (mt * 16 + cl) * 128 + swz;
            short8 aA = *(const short8*)(lA + off);
            short8 aH = *(const short8*)(lH + off);
            short8 aP = *(const short8*)(lP + off);
            #pragma unroll
            for (int nt = 0; nt < 2; ++nt) {
                accM[mt][nt] = __builtin_amdgcn_mfma_f32_16x16x32_bf16(
                    aA, bn[nt], accM[mt][nt], 0, 0, 0);
                accM[mt][nt] = __builtin_amdgcn_mfma_f32_16x16x32_bf16(
                    aH, bl[nt], accM[mt][nt], 0, 0, 0);
                accG[mt][nt] = __builtin_amdgcn_mfma_f32_16x16x32_bf16(
                    aP, bs[nt], accG[mt][nt], 0, 0, 0);
            }
        }
    }

    float b0 = bias[ncb + cl], b1 = bias[ncb + 16 + cl];

    // ---- epilogue: C/D layout col = lane&15, row = quad*4 + reg.
    // prevh bf16 from LDS pB (swizzled).
    #pragma unroll
    for (int mt = 0; mt < 4; ++mt) {
        #pragma unroll
        for (int r = 0; r < 4; ++r) {
            int nrow = mt * 16 + q * 4 + r;
            int node = node_base + nrow;
            if (node >= nN) continue;
            #pragma unroll
            for (int nt = 0; nt < 2; ++nt) {
                int col = ncb + nt * 16 + cl;
                float pv = bfu(lP[nrow * 128 +
                                  ((((col >> 3) ^ (nrow & 15)) << 3) | (col & 7))]);
                float sg = 1.0f / (1.0f + __expf(-(accG[mt][nt][r] + (nt ? b1 : b0))));
                float o  = sg * accM[mt][nt][r] + (1.0f - sg) * pv;
                out[(size_t)node * DD + col] = (o > 0.f ? o : 0.f);
            }
        }
    }
}

// ---- patch deg==0 nodes exactly (fp32)
__global__ __launch_bounds__(256) void fix_k(
    const float* __restrict__ h, const float* __restrict__ prevh,
    const float* __restrict__ bias, const float* __restrict__ We,
    const float* __restrict__ Wsk, const int* __restrict__ deg,
    float* __restrict__ out, int nN, int chunk) {
    __shared__ int list[256];
    __shared__ int cnt;
    __shared__ float hrow[DD], prow[DD], res[2][DD];
    int tid = threadIdx.x;
    int base = blockIdx.x * chunk;
    for (int c = base; c < base + chunk && c < nN; c += 256) {
        if (tid == 0) cnt = 0;
        __syncthreads();
        int v = c + tid;
        if (v < nN && v < base + chunk && deg[v] == 0)
            list[atomicAdd(&cnt, 1)] = v;
        __syncthreads();
        int m = cnt;
        for (int i = 0; i < m; ++i) {
            int node = list[i];
            if (tid < DD) hrow[tid] = h[(size_t)node * DD + tid];
            else prow[tid - DD] = prevh[(size_t)node * DD + tid - DD];
            __syncthreads();
            int col = tid & (DD - 1);
            int half = tid >> 7;
            const float* W = half ? Wsk : We;
            const float* x = half ? prow : hrow;
            float s = 0.f;
            for (int k = 0; k < DD; ++k) s += x[k] * W[k * DD + col];
            res[half][col] = s;
            __syncthreads();
            if (tid < DD) {
                float sg = 1.0f / (1.0f + __expf(-(res[1][col] + bias[col])));
                float o  = sg * res[0][col] + (1.0f - sg) * prow[col];
                out[(size_t)node * DD + col] = (o > 0.f ? o : 0.f);
            }
            __syncthreads();
        }
        __syncthreads();
    }
}

extern "C" void kernel_launch(void* const* d_in, const int* in_sizes, int n_in,
                              void* d_out, int out_size, void* d_ws, size_t ws_size,
                              hipStream_t stream) {
    const float* h     = (const float*)d_in[0];
    const float* prevh = (const float*)d_in[1];
    const float* emb   = (const float*)d_in[2];
    const float* normv = (const float*)d_in[3];
    const float* Wn    = (const float*)d_in[4];
    const float* Wl    = (const float*)d_in[5];
    const float* We    = (const float*)d_in[6];
    const float* Wsk   = (const float*)d_in[7];
    const float* bias  = (const float*)d_in[8];
    const int* src   = (const int*)d_in[9];
    const int* dst   = (const int*)d_in[10];
    const int* etype = (const int*)d_in[11];

    int nN = in_sizes[3];       // norm is [N,1]
    int nE = in_sizes[9];
    int nEmbEl = in_sizes[2];   // NUM_RELS * 128

    // ws: Wt 96KB (Wn,Wl,Wsk) | embB | deg off cursor bsum | edges u32 | hB
    char* w = (char*)d_ws;
    size_t o = 0;
    unsigned short* Wt = (unsigned short*)(w + o);  o += 3 * DD * DD * 2;
    unsigned short* embB = (unsigned short*)(w + o); o += ((size_t)nEmbEl * 2 + 255) & ~(size_t)255;
    int* deg    = (int*)(w + o);  o += ((size_t)nN * 4 + 15) & ~(size_t)15;
    int* offA   = (int*)(w + o);  o += ((size_t)nN * 4 + 15) & ~(size_t)15;
    int* cursor = (int*)(w + o);  o += ((size_t)nN * 4 + 15) & ~(size_t)15;
    int* bsum   = (int*)(w + o);  o += 4096;
    unsigned int* edges = (unsigned int*)(w + o); o += ((size_t)nE * 4 + 15) & ~(size_t)15;
    unsigned short* hB = (unsigned short*)(w + o);

    int totalH = nN * DD;
    int nConvH = (totalH + 8191) / 8192;
    int nEmbB  = (nEmbEl + 2047) / 2048;
    int nHistB = (nE + 1023) / 1024;
    int nB = (nN + 1023) / 1024;

    hipMemsetAsync(deg, 0, (size_t)nN * sizeof(int), stream);
    prep_k<<<nHistB + nConvH + 48 + nEmbB, 256, 0, stream>>>(
        h, Wn, Wl, Wsk, emb, dst, hB, embB, Wt, deg, nN, nEmbEl, nE);
    scan1_k<<<nB, 1024, 0, stream>>>(deg, offA, bsum, nN);
    scan23_k<<<nB, 1024, 0, stream>>>(bsum, offA, cursor, nN, nB);
    sort_k<<<(nE + 255) / 256, 256, 0, stream>>>(src, dst, etype, nE, cursor, edges);
    gather_k<<<(nN + 3) / 4, 256, 0, stream>>>(hB, embB, edges, offA, deg, normv,
                                               (char*)d_out, nN);
    fused_k<<<(nN + 63) / 64, 256, 0, stream>>>(hB, prevh, bias, (const char*)d_out,
                                                Wt, (float*)d_out, nN);
    int fgrid = 256;
    int chunk = ((nN + fgrid * 256 - 1) / (fgrid * 256)) * 256;
    fix_k<<<fgrid, 256, 0, stream>>>(h, prevh, bias, We, Wsk, deg, (float*)d_out,
                                     nN, chunk);
    (void)ws_size; (void)n_in; (void)out_size;
}

// Round 4
// 311.781 us; speedup vs baseline: 1.1662x; 1.0198x over previous
//
#include <hip/hip_runtime.h>

#define DD 128

typedef __attribute__((ext_vector_type(8))) short short8;
typedef __attribute__((ext_vector_type(4))) float f32x4;
typedef __attribute__((ext_vector_type(4))) int i32x4;

__device__ __forceinline__ unsigned short f2bf(float f) {
    union { float f; unsigned int i; } c; c.f = f;
    unsigned int x = c.i;
    return (unsigned short)((x + 0x7fffu + ((x >> 16) & 1u)) >> 16);
}
__device__ __forceinline__ float bfu(unsigned short u) {
    union { unsigned int i; float f; } c; c.i = ((unsigned int)u) << 16; return c.f;
}
// async 16B global -> LDS (dest is wave-uniform base + lane*16)
__device__ __forceinline__ void gload_lds16(const void* g, void* l) {
    __builtin_amdgcn_global_load_lds(
        (const __attribute__((address_space(1))) unsigned int*)g,
        (__attribute__((address_space(3))) unsigned int*)l, 16, 0, 0);
}
// Index accessor robust to int32 vs int64 (little-endian, nonneg values < 2^31)
__device__ __forceinline__ int idx_at(const int* p, int e, int is64) {
    return is64 ? p[2 * e] : p[e];
}
// Per-block int64 detection: int64 => odd 32-bit words (high halves) all zero.
__device__ __forceinline__ int block_is64(const int* dst, int nE, int* s_flag) {
    if (threadIdx.x == 0) *s_flag = 0;
    __syncthreads();
    int w = 2 * (int)threadIdx.x + 1;
    if (threadIdx.x < 128 && w < nE && dst[w] != 0) atomicOr(s_flag, 1);
    __syncthreads();
    return !*s_flag;
}

// ---- prep: one kernel, roles by blockIdx (histogram first so the scattered
// atomics overlap the streaming conversion):
// [0, nHistB)   : in-degree histogram, 4 edges/thread (deg pre-zeroed)
// [+nConvH)     : h fp32 -> hB bf16, 8192 elems/block, 8 loads in flight
// [+48)         : 3 weights transposed+converted into Wt
// [+nEmbB)      : emb fp32 -> embB bf16
__global__ __launch_bounds__(256) void prep_k(
    const float* __restrict__ h,
    const float* __restrict__ W0, const float* __restrict__ W1,
    const float* __restrict__ W2, const float* __restrict__ emb,
    const int* __restrict__ dst,
    unsigned short* __restrict__ hB,
    unsigned short* __restrict__ embB, unsigned short* __restrict__ Wt,
    int* __restrict__ deg, int nN, int nEmbEl, int nE) {
    int tid = threadIdx.x;
    int bid = blockIdx.x;
    int nHistB = (nE + 1023) / 1024;
    if (bid < nHistB) {
        __shared__ int s_flag;
        int is64 = block_is64(dst, nE, &s_flag);
        int e0 = bid * 1024 + tid * 4;
        #pragma unroll
        for (int j = 0; j < 4; ++j) {
            int e = e0 + j;
            if (e < nE) atomicAdd(deg + idx_at(dst, e, is64), 1);
        }
        return;
    }
    bid -= nHistB;
    int totalH = nN * DD;
    int nConvH = (totalH + 8191) / 8192;
    if (bid < nConvH) {
        int base0 = bid * 8192;
        if (base0 + 8192 <= totalH) {
            int base = base0 + tid * 8;
            f32x4 x[4][2];
            #pragma unroll
            for (int i = 0; i < 4; ++i) {
                x[i][0] = *(const f32x4*)(h + base + i * 2048);
                x[i][1] = *(const f32x4*)(h + base + i * 2048 + 4);
            }
            #pragma unroll
            for (int i = 0; i < 4; ++i) {
                short8 p;
                #pragma unroll
                for (int j = 0; j < 4; ++j) {
                    p[j]     = (short)f2bf(x[i][0][j]);
                    p[4 + j] = (short)f2bf(x[i][1][j]);
                }
                *(short8*)(hB + base + i * 2048) = p;
            }
        } else {
            #pragma unroll
            for (int i = 0; i < 4; ++i) {
                int b2 = base0 + i * 2048 + tid * 8;
                if (b2 + 8 <= totalH) {
                    f32x4 x0 = *(const f32x4*)(h + b2);
                    f32x4 x1 = *(const f32x4*)(h + b2 + 4);
                    short8 p;
                    #pragma unroll
                    for (int j = 0; j < 4; ++j) {
                        p[j]     = (short)f2bf(x0[j]);
                        p[4 + j] = (short)f2bf(x1[j]);
                    }
                    *(short8*)(hB + b2) = p;
                } else {
                    for (int j = b2; j < totalH && j < b2 + 8; ++j)
                        hB[j] = f2bf(h[j]);
                }
            }
        }
        return;
    }
    bid -= nConvH;
    if (bid < 48) {
        const float* Ws[3] = {W0, W1, W2};
        int w = bid >> 4, chunk = bid & 15;
        unsigned short* T = Wt + w * (DD * DD);
        #pragma unroll
        for (int i = 0; i < 4; ++i) {
            int t = chunk * 1024 + i * 256 + tid;
            int n = t >> 7, k = t & 127;
            T[t] = f2bf(Ws[w][k * DD + n]);
        }
        return;
    }
    bid -= 48;
    // emb role
    int base = bid * 2048 + tid * 8;
    if (base + 8 <= nEmbEl) {
        f32x4 x0 = *(const f32x4*)(emb + base);
        f32x4 x1 = *(const f32x4*)(emb + base + 4);
        short8 p;
        #pragma unroll
        for (int j = 0; j < 4; ++j) {
            p[j]     = (short)f2bf(x0[j]);
            p[4 + j] = (short)f2bf(x1[j]);
        }
        *(short8*)(embB + base) = p;
    } else {
        for (int j = base; j < nEmbEl; ++j) embB[j] = f2bf(emb[j]);
    }
}

// ---- exclusive scan, step 1
__global__ __launch_bounds__(1024) void scan1_k(const int* deg, int* off, int* bsum,
                                                int nN) {
    __shared__ int s[1024];
    int t = threadIdx.x, i = blockIdx.x * 1024 + t;
    int v = (i < nN) ? deg[i] : 0;
    s[t] = v;
    __syncthreads();
    for (int d = 1; d < 1024; d <<= 1) {
        int x = (t >= d) ? s[t - d] : 0;
        __syncthreads();
        s[t] += x;
        __syncthreads();
    }
    if (i < nN) off[i] = s[t] - v;
    if (t == 1023) bsum[blockIdx.x] = s[1023];
}

// ---- steps 2+3 merged
__global__ __launch_bounds__(1024) void scan23_k(const int* bsum, int* off,
                                                 int* cursor, int nN, int nB) {
    __shared__ int s[1024];
    int t = threadIdx.x;
    s[t] = (t < nB) ? bsum[t] : 0;
    __syncthreads();
    for (int d = 1; d < 1024; d <<= 1) {
        int x = (t >= d) ? s[t - d] : 0;
        __syncthreads();
        s[t] += x;
        __syncthreads();
    }
    int base = (blockIdx.x == 0) ? 0 : s[blockIdx.x - 1];
    int i = blockIdx.x * 1024 + t;
    if (i < nN) {
        int o = off[i] + base;
        off[i] = o;
        cursor[i] = o;
    }
}

// ---- counting sort: packed edge word = src | (etype<<17); bucketed by dst
__global__ __launch_bounds__(256) void sort_k(const int* src, const int* dst,
                                              const int* et, int nE,
                                              int* cursor, unsigned int* edges) {
    __shared__ int s_flag;
    int is64 = block_is64(dst, nE, &s_flag);
    int e = blockIdx.x * 256 + threadIdx.x;
    if (e >= nE) return;
    int d = idx_at(dst, e, is64);
    int pos = atomicAdd(cursor + d, 1);
    edges[pos] = (unsigned int)idx_at(src, e, is64) |
                 ((unsigned int)idx_at(et, e, is64) << 17);
}

// ---- CSR gather, all-bf16: agg[v] = norm[v] * sum (hB[src]+embB[etype]);
// 16 lanes per edge; 8 edges per iteration. Packed bf16 into first 256B of slot.
__global__ __launch_bounds__(256) void gather_k(
    const unsigned short* __restrict__ hB, const unsigned short* __restrict__ embB,
    const unsigned int* __restrict__ edges, const int* __restrict__ off,
    const int* __restrict__ deg, const float* __restrict__ normv,
    char* __restrict__ aggP, int nN) {
    int lane = threadIdx.x & 63;
    int v = blockIdx.x * 4 + (threadIdx.x >> 6);
    if (v >= nN) return;
    int slot = lane >> 4, l16 = lane & 15;
    int b = off[v], n = deg[v];
    float a[8] = {0.f, 0.f, 0.f, 0.f, 0.f, 0.f, 0.f, 0.f};
    for (int base = 0; base < n; base += 8) {
        int m0 = base + slot, m1 = base + 4 + slot;
        bool v0 = m0 < n, v1 = m1 < n;
        unsigned int w0 = 0, w1 = 0;
        if (v0) w0 = edges[b + m0];
        if (v1) w1 = edges[b + m1];
        short8 hv0, rv0, hv1, rv1;
        if (v0) {
            hv0 = *(const short8*)(hB + (size_t)(w0 & 0x1FFFFu) * DD + l16 * 8);
            rv0 = *(const short8*)(embB + (size_t)(w0 >> 17) * DD + l16 * 8);
        }
        if (v1) {
            hv1 = *(const short8*)(hB + (size_t)(w1 & 0x1FFFFu) * DD + l16 * 8);
            rv1 = *(const short8*)(embB + (size_t)(w1 >> 17) * DD + l16 * 8);
        }
        if (v0) {
            #pragma unroll
            for (int j = 0; j < 8; ++j)
                a[j] += bfu((unsigned short)hv0[j]) + bfu((unsigned short)rv0[j]);
        }
        if (v1) {
            #pragma unroll
            for (int j = 0; j < 8; ++j)
                a[j] += bfu((unsigned short)hv1[j]) + bfu((unsigned short)rv1[j]);
        }
    }
    #pragma unroll
    for (int j = 0; j < 8; ++j) {
        a[j] += __shfl_xor(a[j], 16);
        a[j] += __shfl_xor(a[j], 32);
    }
    if (slot == 0) {
        float nm = normv[v];
        short8 p;
        #pragma unroll
        for (int j = 0; j < 8; ++j) p[j] = (short)f2bf(a[j] * nm);
        *(short8*)(aggP + (size_t)v * 512 + l16 * 16) = p;
    }
}

// ---- fused 3-GEMM + epilogue: persistent double-buffered pipeline.
// Grid = 256 (1 block/CU), each block grid-strides over 64-node tiles with
// 2-deep LDS double buffering (2 x 3 slabs x 16KB = 96KB dynamic LDS).
// Per iteration: issue ALL of tile t+1's loads (gload_lds agg+hB, f32x4 prevh
// to regs) BEFORE computing tile t (T14 issue-early/write-late), then convert+
// ds_write prevh, one barrier. Wt B-fragments (24 x short8 = 96 VGPR) hoisted
// out of the loop -- occupancy is LDS-capped at 1 block/CU anyway, so the
// register file is free. Swizzle: both-sides chunk XOR (c ^ (row&15)).
// deg==0 rows patched exactly by fix_k afterwards.
__global__ __launch_bounds__(256, 1) void fused_k(
    const unsigned short* __restrict__ hB,
    const float* __restrict__ prevh,
    const float* __restrict__ bias,
    const char* __restrict__ aggP,       // = d_out: [0,256) of each 512B slot = agg bf16
    const unsigned short* __restrict__ Wt,
    float* __restrict__ out, int nN, int nTiles) {
    extern __shared__ unsigned short lds[];   // 2 * 24576 u16 = 96KB
    const int lane = threadIdx.x & 63;
    const int wv = threadIdx.x >> 6;
    const int q = lane >> 4, cl = lane & 15;
    const int ncb = wv * 32;
    const int stride = gridDim.x;

    int t = blockIdx.x;
    if (t >= nTiles) return;

    // hoisted Wt fragments (loop-invariant; L2-resident)
    short8 bn[4][2], bl[4][2], bs[4][2];
    #pragma unroll
    for (int ks = 0; ks < 4; ++ks)
        #pragma unroll
        for (int nt = 0; nt < 2; ++nt) {
            int n = (ncb + nt * 16 + cl) * DD + ks * 32 + q * 8;
            bn[ks][nt] = *(const short8*)(Wt + n);
            bl[ks][nt] = *(const short8*)(Wt + DD * DD + n);
            bs[ks][nt] = *(const short8*)(Wt + 2 * DD * DD + n);
        }
    const float b0 = bias[ncb + cl], b1 = bias[ncb + 16 + cl];

    const int r0 = lane >> 4;      // 0..3  (staging row-in-group)
    const int c16 = lane & 15;     // staging chunk

    // ---- prologue: stage tile t into buffer 0
    {
        int node_base = t * 64;
        #pragma unroll
        for (int it = 0; it < 4; ++it) {
            int r = it * 16 + wv * 4 + r0;
            int row = node_base + r; if (row > nN - 1) row = nN - 1;
            int sw = (c16 ^ (r & 15)) << 4;
            char* bptr = (char*)lds + (it * 16 + wv * 4) * 256;
            gload_lds16(aggP + (size_t)row * 512 + sw, bptr);
            gload_lds16((const char*)hB + (size_t)row * 256 + sw, bptr + 16384);
        }
        f32x4 p0[4], p1[4];
        #pragma unroll
        for (int it = 0; it < 4; ++it) {
            int pos = it * 512 + lane * 8;
            int node = node_base + wv * 16 + (pos >> 7);
            if (node > nN - 1) node = nN - 1;
            const float* g = prevh + (size_t)node * DD + (pos & 127);
            p0[it] = *(const f32x4*)g;
            p1[it] = *(const f32x4*)(g + 4);
        }
        #pragma unroll
        for (int it = 0; it < 4; ++it) {
            int pos = it * 512 + lane * 8;
            int r = wv * 16 + (pos >> 7);
            int c = (pos & 127) >> 3;
            short8 p;
            #pragma unroll
            for (int j = 0; j < 4; ++j) {
                p[j]     = (short)f2bf(p0[it][j]);
                p[4 + j] = (short)f2bf(p1[it][j]);
            }
            *(short8*)((char*)lds + 32768 + r * 256 + ((c ^ (r & 15)) << 4)) = p;
        }
    }
    __syncthreads();

    int cur = 0;
    for (;;) {
        int node_base = t * 64;
        int tn = t + stride;
        bool more = (tn < nTiles);

        // ---- prefetch tile tn into buffer cur^1 (issue-early)
        f32x4 p0[4], p1[4];
        if (more) {
            int nb2 = tn * 64;
            char* dbuf = (char*)lds + (cur ^ 1) * 49152;
            #pragma unroll
            for (int it = 0; it < 4; ++it) {
                int r = it * 16 + wv * 4 + r0;
                int row = nb2 + r; if (row > nN - 1) row = nN - 1;
                int sw = (c16 ^ (r & 15)) << 4;
                char* bptr = dbuf + (it * 16 + wv * 4) * 256;
                gload_lds16(aggP + (size_t)row * 512 + sw, bptr);
                gload_lds16((const char*)hB + (size_t)row * 256 + sw, bptr + 16384);
            }
            #pragma unroll
            for (int it = 0; it < 4; ++it) {
                int pos = it * 512 + lane * 8;
                int node = nb2 + wv * 16 + (pos >> 7);
                if (node > nN - 1) node = nN - 1;
                const float* g = prevh + (size_t)node * DD + (pos & 127);
                p0[it] = *(const f32x4*)g;
                p1[it] = *(const f32x4*)(g + 4);
            }
        }

        // ---- compute tile t from buffer cur
        const unsigned short* lA = lds + cur * 24576;
        const unsigned short* lH = lA + 8192;
        const unsigned short* lP = lA + 16384;

        f32x4 accM[4][2], accG[4][2];
        #pragma unroll
        for (int mt = 0; mt < 4; ++mt)
            #pragma unroll
            for (int nt = 0; nt < 2; ++nt) {
                accM[mt][nt] = (f32x4){0.f, 0.f, 0.f, 0.f};
                accG[mt][nt] = (f32x4){0.f, 0.f, 0.f, 0.f};
            }
        #pragma unroll
        for (int ks = 0; ks < 4; ++ks) {
            int swz = ((ks * 4 + q) ^ cl) << 3;
            #pragma unroll
            for (int mt = 0; mt < 4; ++mt) {
                int off = (mt * 16 + cl) * 128 + swz;
                short8 aA = *(const short8*)(lA + off);
                short8 aH = *(const short8*)(lH + off);
                short8 aP = *(const short8*)(lP + off);
                #pragma unroll
                for (int nt = 0; nt < 2; ++nt) {
                    accM[mt][nt] = __builtin_amdgcn_mfma_f32_16x16x32_bf16(
                        aA, bn[ks][nt], accM[mt][nt], 0, 0, 0);
                    accM[mt][nt] = __builtin_amdgcn_mfma_f32_16x16x32_bf16(
                        aH, bl[ks][nt], accM[mt][nt], 0, 0, 0);
                    accG[mt][nt] = __builtin_amdgcn_mfma_f32_16x16x32_bf16(
                        aP, bs[ks][nt], accG[mt][nt], 0, 0, 0);
                }
            }
        }

        // ---- epilogue: C/D layout col = lane&15, row = quad*4 + reg
        #pragma unroll
        for (int mt = 0; mt < 4; ++mt) {
            #pragma unroll
            for (int r = 0; r < 4; ++r) {
                int nrow = mt * 16 + q * 4 + r;
                int node = node_base + nrow;
                if (node >= nN) continue;
                #pragma unroll
                for (int nt = 0; nt < 2; ++nt) {
                    int col = ncb + nt * 16 + cl;
                    float pv = bfu(lP[nrow * 128 +
                                      ((((col >> 3) ^ (nrow & 15)) << 3) | (col & 7))]);
                    float sg = 1.0f / (1.0f + __expf(-(accG[mt][nt][r] +
                                                       (nt ? b1 : b0))));
                    float o  = sg * accM[mt][nt][r] + (1.0f - sg) * pv;
                    out[(size_t)node * DD + col] = (o > 0.f ? o : 0.f);
                }
            }
        }

        // ---- write-late: prevh of tile tn -> PB slab of buffer cur^1
        if (more) {
            char* dbuf = (char*)lds + (cur ^ 1) * 49152;
            #pragma unroll
            for (int it = 0; it < 4; ++it) {
                int pos = it * 512 + lane * 8;
                int r = wv * 16 + (pos >> 7);
                int c = (pos & 127) >> 3;
                short8 p;
                #pragma unroll
                for (int j = 0; j < 4; ++j) {
                    p[j]     = (short)f2bf(p0[it][j]);
                    p[4 + j] = (short)f2bf(p1[it][j]);
                }
                *(short8*)(dbuf + 32768 + r * 256 + ((c ^ (r & 15)) << 4)) = p;
            }
        }
        __syncthreads();
        if (!more) break;
        cur ^= 1;
        t = tn;
    }
}

// ---- patch deg==0 nodes exactly (fp32)
__global__ __launch_bounds__(256) void fix_k(
    const float* __restrict__ h, const float* __restrict__ prevh,
    const float* __restrict__ bias, const float* __restrict__ We,
    const float* __restrict__ Wsk, const int* __restrict__ deg,
    float* __restrict__ out, int nN, int chunk) {
    __shared__ int list[256];
    __shared__ int cnt;
    __shared__ float hrow[DD], prow[DD], res[2][DD];
    int tid = threadIdx.x;
    int base = blockIdx.x * chunk;
    for (int c = base; c < base + chunk && c < nN; c += 256) {
        if (tid == 0) cnt = 0;
        __syncthreads();
        int v = c + tid;
        if (v < nN && v < base + chunk && deg[v] == 0)
            list[atomicAdd(&cnt, 1)] = v;
        __syncthreads();
        int m = cnt;
        for (int i = 0; i < m; ++i) {
            int node = list[i];
            if (tid < DD) hrow[tid] = h[(size_t)node * DD + tid];
            else prow[tid - DD] = prevh[(size_t)node * DD + tid - DD];
            __syncthreads();
            int col = tid & (DD - 1);
            int half = tid >> 7;
            const float* W = half ? Wsk : We;
            const float* x = half ? prow : hrow;
            float s = 0.f;
            for (int k = 0; k < DD; ++k) s += x[k] * W[k * DD + col];
            res[half][col] = s;
            __syncthreads();
            if (tid < DD) {
                float sg = 1.0f / (1.0f + __expf(-(res[1][col] + bias[col])));
                float o  = sg * res[0][col] + (1.0f - sg) * prow[col];
                out[(size_t)node * DD + col] = (o > 0.f ? o : 0.f);
            }
            __syncthreads();
        }
        __syncthreads();
    }
}

extern "C" void kernel_launch(void* const* d_in, const int* in_sizes, int n_in,
                              void* d_out, int out_size, void* d_ws, size_t ws_size,
                              hipStream_t stream) {
    const float* h     = (const float*)d_in[0];
    const float* prevh = (const float*)d_in[1];
    const float* emb   = (const float*)d_in[2];
    const float* normv = (const float*)d_in[3];
    const float* Wn    = (const float*)d_in[4];
    const float* Wl    = (const float*)d_in[5];
    const float* We    = (const float*)d_in[6];
    const float* Wsk   = (const float*)d_in[7];
    const float* bias  = (const float*)d_in[8];
    const int* src   = (const int*)d_in[9];
    const int* dst   = (const int*)d_in[10];
    const int* etype = (const int*)d_in[11];

    int nN = in_sizes[3];       // norm is [N,1]
    int nE = in_sizes[9];
    int nEmbEl = in_sizes[2];   // NUM_RELS * 128

    // ws: Wt 96KB (Wn,Wl,Wsk) | embB | deg off cursor bsum | edges u32 | hB
    char* w = (char*)d_ws;
    size_t o = 0;
    unsigned short* Wt = (unsigned short*)(w + o);  o += 3 * DD * DD * 2;
    unsigned short* embB = (unsigned short*)(w + o); o += ((size_t)nEmbEl * 2 + 255) & ~(size_t)255;
    int* deg    = (int*)(w + o);  o += ((size_t)nN * 4 + 15) & ~(size_t)15;
    int* offA   = (int*)(w + o);  o += ((size_t)nN * 4 + 15) & ~(size_t)15;
    int* cursor = (int*)(w + o);  o += ((size_t)nN * 4 + 15) & ~(size_t)15;
    int* bsum   = (int*)(w + o);  o += 4096;
    unsigned int* edges = (unsigned int*)(w + o); o += ((size_t)nE * 4 + 15) & ~(size_t)15;
    unsigned short* hB = (unsigned short*)(w + o);

    int totalH = nN * DD;
    int nConvH = (totalH + 8191) / 8192;
    int nEmbB  = (nEmbEl + 2047) / 2048;
    int nHistB = (nE + 1023) / 1024;
    int nB = (nN + 1023) / 1024;
    int nTiles = (nN + 63) / 64;
    int fgrid2 = nTiles < 256 ? nTiles : 256;

    hipMemsetAsync(deg, 0, (size_t)nN * sizeof(int), stream);
    prep_k<<<nHistB + nConvH + 48 + nEmbB, 256, 0, stream>>>(
        h, Wn, Wl, Wsk, emb, dst, hB, embB, Wt, deg, nN, nEmbEl, nE);
    scan1_k<<<nB, 1024, 0, stream>>>(deg, offA, bsum, nN);
    scan23_k<<<nB, 1024, 0, stream>>>(bsum, offA, cursor, nN, nB);
    sort_k<<<(nE + 255) / 256, 256, 0, stream>>>(src, dst, etype, nE, cursor, edges);
    gather_k<<<(nN + 3) / 4, 256, 0, stream>>>(hB, embB, edges, offA, deg, normv,
                                               (char*)d_out, nN);
    fused_k<<<fgrid2, 256, 98304, stream>>>(hB, prevh, bias, (const char*)d_out,
                                            Wt, (float*)d_out, nN, nTiles);
    int fgrid = 256;
    int chunk = ((nN + fgrid * 256 - 1) / (fgrid * 256)) * 256;
    fix_k<<<fgrid, 256, 0, stream>>>(h, prevh, bias, We, Wsk, deg, (float*)d_out,
                                     nN, chunk);
    (void)ws_size; (void)n_in; (void)out_size;
}

// Round 5
// 292.000 us; speedup vs baseline: 1.2452x; 1.0677x over previous
//
#include <hip/hip_runtime.h>

#define DD 128
#define SCHUNK 4096

typedef __attribute__((ext_vector_type(8))) short short8;
typedef __attribute__((ext_vector_type(4))) float f32x4;
typedef __attribute__((ext_vector_type(4))) int i32x4;

__device__ __forceinline__ unsigned short f2bf(float f) {
    union { float f; unsigned int i; } c; c.f = f;
    unsigned int x = c.i;
    return (unsigned short)((x + 0x7fffu + ((x >> 16) & 1u)) >> 16);
}
__device__ __forceinline__ float bfu(unsigned short u) {
    union { unsigned int i; float f; } c; c.i = ((unsigned int)u) << 16; return c.f;
}
// async 16B global -> LDS (dest is wave-uniform base + lane*16)
__device__ __forceinline__ void gload_lds16(const void* g, void* l) {
    __builtin_amdgcn_global_load_lds(
        (const __attribute__((address_space(1))) unsigned int*)g,
        (__attribute__((address_space(3))) unsigned int*)l, 16, 0, 0);
}
// Index accessor robust to int32 vs int64 (little-endian, nonneg values < 2^31)
__device__ __forceinline__ int idx_at(const int* p, int e, int is64) {
    return is64 ? p[2 * e] : p[e];
}
// Per-block int64 detection: int64 => odd 32-bit words (high halves) all zero.
__device__ __forceinline__ int block_is64(const int* dst, int nE, int* s_flag) {
    if (threadIdx.x == 0) *s_flag = 0;
    __syncthreads();
    int w = 2 * (int)threadIdx.x + 1;
    if (threadIdx.x < 128 && w < nE && dst[w] != 0) atomicOr(s_flag, 1);
    __syncthreads();
    return !*s_flag;
}

// ---- prep: one kernel, roles by blockIdx (histogram first so the scattered
// atomics overlap the streaming conversion):
// [0, nHistB)   : in-degree histogram, 4 edges/thread (deg pre-zeroed)
// [+nConvH)     : h fp32 -> hB bf16, 8192 elems/block, 8 loads in flight
// [+48)         : 3 weights transposed+converted into Wt
// [+nEmbB)      : emb fp32 -> embB bf16
__global__ __launch_bounds__(256) void prep_k(
    const float* __restrict__ h,
    const float* __restrict__ W0, const float* __restrict__ W1,
    const float* __restrict__ W2, const float* __restrict__ emb,
    const int* __restrict__ dst,
    unsigned short* __restrict__ hB,
    unsigned short* __restrict__ embB, unsigned short* __restrict__ Wt,
    int* __restrict__ deg, int nN, int nEmbEl, int nE) {
    int tid = threadIdx.x;
    int bid = blockIdx.x;
    int nHistB = (nE + 1023) / 1024;
    if (bid < nHistB) {
        __shared__ int s_flag;
        int is64 = block_is64(dst, nE, &s_flag);
        int e0 = bid * 1024 + tid * 4;
        #pragma unroll
        for (int j = 0; j < 4; ++j) {
            int e = e0 + j;
            if (e < nE) atomicAdd(deg + idx_at(dst, e, is64), 1);
        }
        return;
    }
    bid -= nHistB;
    int totalH = nN * DD;
    int nConvH = (totalH + 8191) / 8192;
    if (bid < nConvH) {
        int base0 = bid * 8192;
        if (base0 + 8192 <= totalH) {
            int base = base0 + tid * 8;
            f32x4 x[4][2];
            #pragma unroll
            for (int i = 0; i < 4; ++i) {
                x[i][0] = *(const f32x4*)(h + base + i * 2048);
                x[i][1] = *(const f32x4*)(h + base + i * 2048 + 4);
            }
            #pragma unroll
            for (int i = 0; i < 4; ++i) {
                short8 p;
                #pragma unroll
                for (int j = 0; j < 4; ++j) {
                    p[j]     = (short)f2bf(x[i][0][j]);
                    p[4 + j] = (short)f2bf(x[i][1][j]);
                }
                *(short8*)(hB + base + i * 2048) = p;
            }
        } else {
            #pragma unroll
            for (int i = 0; i < 4; ++i) {
                int b2 = base0 + i * 2048 + tid * 8;
                if (b2 + 8 <= totalH) {
                    f32x4 x0 = *(const f32x4*)(h + b2);
                    f32x4 x1 = *(const f32x4*)(h + b2 + 4);
                    short8 p;
                    #pragma unroll
                    for (int j = 0; j < 4; ++j) {
                        p[j]     = (short)f2bf(x0[j]);
                        p[4 + j] = (short)f2bf(x1[j]);
                    }
                    *(short8*)(hB + b2) = p;
                } else {
                    for (int j = b2; j < totalH && j < b2 + 8; ++j)
                        hB[j] = f2bf(h[j]);
                }
            }
        }
        return;
    }
    bid -= nConvH;
    if (bid < 48) {
        const float* Ws[3] = {W0, W1, W2};
        int w = bid >> 4, chunk = bid & 15;
        unsigned short* T = Wt + w * (DD * DD);
        #pragma unroll
        for (int i = 0; i < 4; ++i) {
            int t = chunk * 1024 + i * 256 + tid;
            int n = t >> 7, k = t & 127;
            T[t] = f2bf(Ws[w][k * DD + n]);
        }
        return;
    }
    bid -= 48;
    // emb role
    int base = bid * 2048 + tid * 8;
    if (base + 8 <= nEmbEl) {
        f32x4 x0 = *(const f32x4*)(emb + base);
        f32x4 x1 = *(const f32x4*)(emb + base + 4);
        short8 p;
        #pragma unroll
        for (int j = 0; j < 4; ++j) {
            p[j]     = (short)f2bf(x0[j]);
            p[4 + j] = (short)f2bf(x1[j]);
        }
        *(short8*)(embB + base) = p;
    } else {
        for (int j = base; j < nEmbEl; ++j) embB[j] = f2bf(emb[j]);
    }
}

// ---- exclusive scan, step 1
__global__ __launch_bounds__(1024) void scan1_k(const int* deg, int* off, int* bsum,
                                                int nN) {
    __shared__ int s[1024];
    int t = threadIdx.x, i = blockIdx.x * 1024 + t;
    int v = (i < nN) ? deg[i] : 0;
    s[t] = v;
    __syncthreads();
    for (int d = 1; d < 1024; d <<= 1) {
        int x = (t >= d) ? s[t - d] : 0;
        __syncthreads();
        s[t] += x;
        __syncthreads();
    }
    if (i < nN) off[i] = s[t] - v;
    if (t == 1023) bsum[blockIdx.x] = s[1023];
}

// ---- steps 2+3 merged; also emits per-bucket (128 nodes) base cursors
__global__ __launch_bounds__(1024) void scan23_k(const int* bsum, int* off,
                                                 int* cursorB, int nN, int nB) {
    __shared__ int s[1024];
    int t = threadIdx.x;
    s[t] = (t < nB) ? bsum[t] : 0;
    __syncthreads();
    for (int d = 1; d < 1024; d <<= 1) {
        int x = (t >= d) ? s[t - d] : 0;
        __syncthreads();
        s[t] += x;
        __syncthreads();
    }
    int base = (blockIdx.x == 0) ? 0 : s[blockIdx.x - 1];
    int i = blockIdx.x * 1024 + t;
    if (i < nN) {
        int o = off[i] + base;
        off[i] = o;
        if ((i & 127) == 0) cursorB[i >> 7] = o;   // bucket run base
    }
}

// ---- sort phase 1: partition edges into coarse buckets (dst>>7) with
// per-(block,bucket) contiguous runs so scattered writes line-merge.
// staged word = src | et<<17 | (dst&127)<<25  (fits: 17+8+7 = 32 bits).
// Requires nBuck <= 2048 (nN <= 262144).
__global__ __launch_bounds__(256) void sort1_k(
    const int* __restrict__ src, const int* __restrict__ dst,
    const int* __restrict__ et, int nE, int nBuck,
    int* __restrict__ cursorB, unsigned int* __restrict__ staging) {
    __shared__ int hist[2048];
    __shared__ int rbase[2048];
    __shared__ unsigned short ranks[SCHUNK];
    __shared__ int s_flag;
    int tid = threadIdx.x;
    int is64 = block_is64(dst, nE, &s_flag);
    for (int i = tid; i < nBuck; i += 256) hist[i] = 0;
    __syncthreads();
    int cbase = blockIdx.x * SCHUNK;
    #pragma unroll
    for (int j = 0; j < SCHUNK / 256; ++j) {
        int e = cbase + j * 256 + tid;
        if (e < nE) {
            int d = idx_at(dst, e, is64);
            ranks[j * 256 + tid] = (unsigned short)atomicAdd(&hist[d >> 7], 1);
        }
    }
    __syncthreads();
    for (int b = tid; b < nBuck; b += 256) {
        int c = hist[b];
        if (c) rbase[b] = atomicAdd(cursorB + b, c);
    }
    __syncthreads();
    #pragma unroll
    for (int j = 0; j < SCHUNK / 256; ++j) {
        int e = cbase + j * 256 + tid;
        if (e < nE) {
            int d = idx_at(dst, e, is64);
            unsigned int wd = (unsigned int)idx_at(src, e, is64) |
                              ((unsigned int)idx_at(et, e, is64) << 17) |
                              ((unsigned int)(d & 127) << 25);
            staging[rbase[d >> 7] + (int)ranks[j * 256 + tid]] = wd;
        }
    }
}

// ---- sort phase 2: one block per bucket; stream the bucket's contiguous
// staging region, scatter to final per-node positions via LDS cursors.
// Writes confined to the block's own small region -> coalesced writeback.
__global__ __launch_bounds__(256) void sort2_k(
    const unsigned int* __restrict__ staging, const int* __restrict__ off,
    int nN, int nE, unsigned int* __restrict__ edges) {
    __shared__ int cur[128];
    int b = blockIdx.x;
    int first = b << 7;
    int tid = threadIdx.x;
    if (tid < 128 && first + tid < nN) cur[tid] = off[first + tid];
    int rStart = off[first];
    int nxt = first + 128;
    int rEnd = (nxt < nN) ? off[nxt] : nE;
    __syncthreads();
    for (int i = rStart + tid; i < rEnd; i += 256) {
        unsigned int wd = staging[i];
        int p = atomicAdd(&cur[wd >> 25], 1);
        edges[p] = wd & 0x1FFFFFFu;
    }
}

// ---- CSR gather, all-bf16: agg[v] = norm[v] * sum (hB[src]+embB[etype]);
// 16 lanes per edge; 8 edges per iteration. Packed bf16 into first 256B of slot.
__global__ __launch_bounds__(256) void gather_k(
    const unsigned short* __restrict__ hB, const unsigned short* __restrict__ embB,
    const unsigned int* __restrict__ edges, const int* __restrict__ off,
    const int* __restrict__ deg, const float* __restrict__ normv,
    char* __restrict__ aggP, int nN) {
    int lane = threadIdx.x & 63;
    int v = blockIdx.x * 4 + (threadIdx.x >> 6);
    if (v >= nN) return;
    int slot = lane >> 4, l16 = lane & 15;
    int b = off[v], n = deg[v];
    float a[8] = {0.f, 0.f, 0.f, 0.f, 0.f, 0.f, 0.f, 0.f};
    for (int base = 0; base < n; base += 8) {
        int m0 = base + slot, m1 = base + 4 + slot;
        bool v0 = m0 < n, v1 = m1 < n;
        unsigned int w0 = 0, w1 = 0;
        if (v0) w0 = edges[b + m0];
        if (v1) w1 = edges[b + m1];
        short8 hv0, rv0, hv1, rv1;
        if (v0) {
            hv0 = *(const short8*)(hB + (size_t)(w0 & 0x1FFFFu) * DD + l16 * 8);
            rv0 = *(const short8*)(embB + (size_t)(w0 >> 17) * DD + l16 * 8);
        }
        if (v1) {
            hv1 = *(const short8*)(hB + (size_t)(w1 & 0x1FFFFu) * DD + l16 * 8);
            rv1 = *(const short8*)(embB + (size_t)(w1 >> 17) * DD + l16 * 8);
        }
        if (v0) {
            #pragma unroll
            for (int j = 0; j < 8; ++j)
                a[j] += bfu((unsigned short)hv0[j]) + bfu((unsigned short)rv0[j]);
        }
        if (v1) {
            #pragma unroll
            for (int j = 0; j < 8; ++j)
                a[j] += bfu((unsigned short)hv1[j]) + bfu((unsigned short)rv1[j]);
        }
    }
    #pragma unroll
    for (int j = 0; j < 8; ++j) {
        a[j] += __shfl_xor(a[j], 16);
        a[j] += __shfl_xor(a[j], 32);
    }
    if (slot == 0) {
        float nm = normv[v];
        short8 p;
        #pragma unroll
        for (int j = 0; j < 8; ++j) p[j] = (short)f2bf(a[j] * nm);
        *(short8*)(aggP + (size_t)v * 512 + l16 * 16) = p;
    }
}

// ---- fused 3-GEMM + epilogue: persistent double-buffered pipeline,
// 32-node tiles, 48KB dynamic LDS -> 2 blocks/CU. While one block drains its
// staging barrier the co-resident block computes (inter-block overlap replaces
// the impossible intra-block one: __syncthreads drains vmcnt(0) including the
// fresh prefetch). Wt fragments hoisted to registers. Swizzle: chunk XOR row.
// deg==0 rows patched exactly by fix_k afterwards.
__global__ __launch_bounds__(256, 2) void fused_k(
    const unsigned short* __restrict__ hB,
    const float* __restrict__ prevh,
    const float* __restrict__ bias,
    const char* __restrict__ aggP,       // = d_out: [0,256) of each 512B slot = agg bf16
    const unsigned short* __restrict__ Wt,
    float* __restrict__ out, int nN, int nTiles) {
    extern __shared__ unsigned short lds[];   // 2 * 12288 u16 = 48KB
    const int lane = threadIdx.x & 63;
    const int wv = threadIdx.x >> 6;
    const int q = lane >> 4, cl = lane & 15;
    const int ncb = wv * 32;
    const int stride = gridDim.x;

    int t = blockIdx.x;
    if (t >= nTiles) return;

    // hoisted Wt fragments (loop-invariant; L2-resident)
    short8 bn[4][2], bl[4][2], bs[4][2];
    #pragma unroll
    for (int ks = 0; ks < 4; ++ks)
        #pragma unroll
        for (int nt = 0; nt < 2; ++nt) {
            int n = (ncb + nt * 16 + cl) * DD + ks * 32 + q * 8;
            bn[ks][nt] = *(const short8*)(Wt + n);
            bl[ks][nt] = *(const short8*)(Wt + DD * DD + n);
            bs[ks][nt] = *(const short8*)(Wt + 2 * DD * DD + n);
        }
    const float b0 = bias[ncb + cl], b1 = bias[ncb + 16 + cl];

    const int r0 = lane >> 4;      // 0..3  (staging row-in-group)
    const int c16 = lane & 15;     // staging chunk

    // ---- prologue: stage tile t into buffer 0
    {
        int node_base = t * 32;
        #pragma unroll
        for (int it = 0; it < 2; ++it) {
            int r = it * 16 + wv * 4 + r0;
            int row = node_base + r; if (row > nN - 1) row = nN - 1;
            int sw = (c16 ^ (r & 15)) << 4;
            char* bptr = (char*)lds + (it * 16 + wv * 4) * 256;
            gload_lds16(aggP + (size_t)row * 512 + sw, bptr);
            gload_lds16((const char*)hB + (size_t)row * 256 + sw, bptr + 8192);
        }
        f32x4 p0[2], p1[2];
        #pragma unroll
        for (int it = 0; it < 2; ++it) {
            int pos = it * 512 + lane * 8;
            int node = node_base + wv * 8 + (pos >> 7);
            if (node > nN - 1) node = nN - 1;
            const float* g = prevh + (size_t)node * DD + (pos & 127);
            p0[it] = *(const f32x4*)g;
            p1[it] = *(const f32x4*)(g + 4);
        }
        #pragma unroll
        for (int it = 0; it < 2; ++it) {
            int pos = it * 512 + lane * 8;
            int r = wv * 8 + (pos >> 7);
            int c = (pos & 127) >> 3;
            short8 p;
            #pragma unroll
            for (int j = 0; j < 4; ++j) {
                p[j]     = (short)f2bf(p0[it][j]);
                p[4 + j] = (short)f2bf(p1[it][j]);
            }
            *(short8*)((char*)lds + 16384 + r * 256 + ((c ^ (r & 15)) << 4)) = p;
        }
    }
    __syncthreads();

    int cur = 0;
    for (;;) {
        int node_base = t * 32;
        int tn = t + stride;
        bool more = (tn < nTiles);

        // ---- prefetch tile tn into buffer cur^1 (issue-early)
        f32x4 p0[2], p1[2];
        if (more) {
            int nb2 = tn * 32;
            char* dbuf = (char*)lds + (cur ^ 1) * 24576;
            #pragma unroll
            for (int it = 0; it < 2; ++it) {
                int r = it * 16 + wv * 4 + r0;
                int row = nb2 + r; if (row > nN - 1) row = nN - 1;
                int sw = (c16 ^ (r & 15)) << 4;
                char* bptr = dbuf + (it * 16 + wv * 4) * 256;
                gload_lds16(aggP + (size_t)row * 512 + sw, bptr);
                gload_lds16((const char*)hB + (size_t)row * 256 + sw, bptr + 8192);
            }
            #pragma unroll
            for (int it = 0; it < 2; ++it) {
                int pos = it * 512 + lane * 8;
                int node = nb2 + wv * 8 + (pos >> 7);
                if (node > nN - 1) node = nN - 1;
                const float* g = prevh + (size_t)node * DD + (pos & 127);
                p0[it] = *(const f32x4*)g;
                p1[it] = *(const f32x4*)(g + 4);
            }
        }

        // ---- compute tile t from buffer cur
        const unsigned short* lA = lds + cur * 12288;
        const unsigned short* lH = lA + 4096;
        const unsigned short* lP = lA + 8192;

        f32x4 accM[2][2], accG[2][2];
        #pragma unroll
        for (int mt = 0; mt < 2; ++mt)
            #pragma unroll
            for (int nt = 0; nt < 2; ++nt) {
                accM[mt][nt] = (f32x4){0.f, 0.f, 0.f, 0.f};
                accG[mt][nt] = (f32x4){0.f, 0.f, 0.f, 0.f};
            }
        #pragma unroll
        for (int ks = 0; ks < 4; ++ks) {
            int swz = ((ks * 4 + q) ^ cl) << 3;
            #pragma unroll
            for (int mt = 0; mt < 2; ++mt) {
                int off = (mt * 16 + cl) * 128 + swz;
                short8 aA = *(const short8*)(lA + off);
                short8 aH = *(const short8*)(lH + off);
                short8 aP = *(const short8*)(lP + off);
                #pragma unroll
                for (int nt = 0; nt < 2; ++nt) {
                    accM[mt][nt] = __builtin_amdgcn_mfma_f32_16x16x32_bf16(
                        aA, bn[ks][nt], accM[mt][nt], 0, 0, 0);
                    accM[mt][nt] = __builtin_amdgcn_mfma_f32_16x16x32_bf16(
                        aH, bl[ks][nt], accM[mt][nt], 0, 0, 0);
                    accG[mt][nt] = __builtin_amdgcn_mfma_f32_16x16x32_bf16(
                        aP, bs[ks][nt], accG[mt][nt], 0, 0, 0);
                }
            }
        }

        // ---- epilogue: C/D layout col = lane&15, row = quad*4 + reg
        #pragma unroll
        for (int mt = 0; mt < 2; ++mt) {
            #pragma unroll
            for (int r = 0; r < 4; ++r) {
                int nrow = mt * 16 + q * 4 + r;
                int node = node_base + nrow;
                if (node >= nN) continue;
                #pragma unroll
                for (int nt = 0; nt < 2; ++nt) {
                    int col = ncb + nt * 16 + cl;
                    float pv = bfu(lP[nrow * 128 +
                                      ((((col >> 3) ^ (nrow & 15)) << 3) | (col & 7))]);
                    float sg = 1.0f / (1.0f + __expf(-(accG[mt][nt][r] +
                                                       (nt ? b1 : b0))));
                    float o  = sg * accM[mt][nt][r] + (1.0f - sg) * pv;
                    out[(size_t)node * DD + col] = (o > 0.f ? o : 0.f);
                }
            }
        }

        // ---- write-late: prevh of tile tn -> PB slab of buffer cur^1
        if (more) {
            char* dbuf = (char*)lds + (cur ^ 1) * 24576;
            #pragma unroll
            for (int it = 0; it < 2; ++it) {
                int pos = it * 512 + lane * 8;
                int r = wv * 8 + (pos >> 7);
                int c = (pos & 127) >> 3;
                short8 p;
                #pragma unroll
                for (int j = 0; j < 4; ++j) {
                    p[j]     = (short)f2bf(p0[it][j]);
                    p[4 + j] = (short)f2bf(p1[it][j]);
                }
                *(short8*)(dbuf + 16384 + r * 256 + ((c ^ (r & 15)) << 4)) = p;
            }
        }
        __syncthreads();
        if (!more) break;
        cur ^= 1;
        t = tn;
    }
}

// ---- patch deg==0 nodes exactly (fp32)
__global__ __launch_bounds__(256) void fix_k(
    const float* __restrict__ h, const float* __restrict__ prevh,
    const float* __restrict__ bias, const float* __restrict__ We,
    const float* __restrict__ Wsk, const int* __restrict__ deg,
    float* __restrict__ out, int nN, int chunk) {
    __shared__ int list[256];
    __shared__ int cnt;
    __shared__ float hrow[DD], prow[DD], res[2][DD];
    int tid = threadIdx.x;
    int base = blockIdx.x * chunk;
    for (int c = base; c < base + chunk && c < nN; c += 256) {
        if (tid == 0) cnt = 0;
        __syncthreads();
        int v = c + tid;
        if (v < nN && v < base + chunk && deg[v] == 0)
            list[atomicAdd(&cnt, 1)] = v;
        __syncthreads();
        int m = cnt;
        for (int i = 0; i < m; ++i) {
            int node = list[i];
            if (tid < DD) hrow[tid] = h[(size_t)node * DD + tid];
            else prow[tid - DD] = prevh[(size_t)node * DD + tid - DD];
            __syncthreads();
            int col = tid & (DD - 1);
            int half = tid >> 7;
            const float* W = half ? Wsk : We;
            const float* x = half ? prow : hrow;
            float s = 0.f;
            for (int k = 0; k < DD; ++k) s += x[k] * W[k * DD + col];
            res[half][col] = s;
            __syncthreads();
            if (tid < DD) {
                float sg = 1.0f / (1.0f + __expf(-(res[1][col] + bias[col])));
                float o  = sg * res[0][col] + (1.0f - sg) * prow[col];
                out[(size_t)node * DD + col] = (o > 0.f ? o : 0.f);
            }
            __syncthreads();
        }
        __syncthreads();
    }
}

extern "C" void kernel_launch(void* const* d_in, const int* in_sizes, int n_in,
                              void* d_out, int out_size, void* d_ws, size_t ws_size,
                              hipStream_t stream) {
    const float* h     = (const float*)d_in[0];
    const float* prevh = (const float*)d_in[1];
    const float* emb   = (const float*)d_in[2];
    const float* normv = (const float*)d_in[3];
    const float* Wn    = (const float*)d_in[4];
    const float* Wl    = (const float*)d_in[5];
    const float* We    = (const float*)d_in[6];
    const float* Wsk   = (const float*)d_in[7];
    const float* bias  = (const float*)d_in[8];
    const int* src   = (const int*)d_in[9];
    const int* dst   = (const int*)d_in[10];
    const int* etype = (const int*)d_in[11];

    int nN = in_sizes[3];       // norm is [N,1]
    int nE = in_sizes[9];
    int nEmbEl = in_sizes[2];   // NUM_RELS * 128

    // ws: Wt 96KB (Wn,Wl,Wsk) | embB | deg off cursorB bsum | edges u32 |
    //     staging u32 | hB    => ~32 MB
    char* w = (char*)d_ws;
    size_t o = 0;
    unsigned short* Wt = (unsigned short*)(w + o);  o += 3 * DD * DD * 2;
    unsigned short* embB = (unsigned short*)(w + o); o += ((size_t)nEmbEl * 2 + 255) & ~(size_t)255;
    int* deg     = (int*)(w + o);  o += ((size_t)nN * 4 + 15) & ~(size_t)15;
    int* offA    = (int*)(w + o);  o += ((size_t)nN * 4 + 15) & ~(size_t)15;
    int* cursorB = (int*)(w + o);  o += 8192;
    int* bsum    = (int*)(w + o);  o += 4096;
    unsigned int* edges   = (unsigned int*)(w + o); o += ((size_t)nE * 4 + 15) & ~(size_t)15;
    unsigned int* staging = (unsigned int*)(w + o); o += ((size_t)nE * 4 + 15) & ~(size_t)15;
    unsigned short* hB = (unsigned short*)(w + o);

    int totalH = nN * DD;
    int nConvH = (totalH + 8191) / 8192;
    int nEmbB  = (nEmbEl + 2047) / 2048;
    int nHistB = (nE + 1023) / 1024;
    int nB = (nN + 1023) / 1024;
    int nBuck = (nN + 127) / 128;          // <= 2048 for nN <= 262144
    int nTiles = (nN + 31) / 32;
    int fgrid2 = nTiles < 512 ? nTiles : 512;

    hipMemsetAsync(deg, 0, (size_t)nN * sizeof(int), stream);
    prep_k<<<nHistB + nConvH + 48 + nEmbB, 256, 0, stream>>>(
        h, Wn, Wl, Wsk, emb, dst, hB, embB, Wt, deg, nN, nEmbEl, nE);
    scan1_k<<<nB, 1024, 0, stream>>>(deg, offA, bsum, nN);
    scan23_k<<<nB, 1024, 0, stream>>>(bsum, offA, cursorB, nN, nB);
    sort1_k<<<(nE + SCHUNK - 1) / SCHUNK, 256, 0, stream>>>(
        src, dst, etype, nE, nBuck, cursorB, staging);
    sort2_k<<<nBuck, 256, 0, stream>>>(staging, offA, nN, nE, edges);
    gather_k<<<(nN + 3) / 4, 256, 0, stream>>>(hB, embB, edges, offA, deg, normv,
                                               (char*)d_out, nN);
    fused_k<<<fgrid2, 256, 49152, stream>>>(hB, prevh, bias, (const char*)d_out,
                                            Wt, (float*)d_out, nN, nTiles);
    int fgrid = 256;
    int chunk = ((nN + fgrid * 256 - 1) / (fgrid * 256)) * 256;
    fix_k<<<fgrid, 256, 0, stream>>>(h, prevh, bias, We, Wsk, deg, (float*)d_out,
                                     nN, chunk);
    (void)ws_size; (void)n_in; (void)out_size;
}

// Round 6
// 281.289 us; speedup vs baseline: 1.2927x; 1.0381x over previous
//
#include <hip/hip_runtime.h>

#define DD 128
#define SCHUNK 4096

typedef __attribute__((ext_vector_type(8))) short short8;
typedef __attribute__((ext_vector_type(4))) float f32x4;
typedef __attribute__((ext_vector_type(2))) float f32x2;
typedef __attribute__((ext_vector_type(4))) int i32x4;
typedef __attribute__((ext_vector_type(4))) unsigned int u32x4;

__device__ __forceinline__ unsigned short f2bf(float f) {
    union { float f; unsigned int i; } c; c.f = f;
    unsigned int x = c.i;
    return (unsigned short)((x + 0x7fffu + ((x >> 16) & 1u)) >> 16);
}
__device__ __forceinline__ float bfu(unsigned short u) {
    union { unsigned int i; float f; } c; c.i = ((unsigned int)u) << 16; return c.f;
}
// unpack u32 of 2 bf16 -> {lo, hi} f32 pair (2 VALU ops, feeds v_pk_add_f32)
__device__ __forceinline__ f32x2 bf2lohi(unsigned int w) {
    union { unsigned int i; float f; } lo, hi;
    lo.i = w << 16;
    hi.i = w & 0xFFFF0000u;
    return (f32x2){lo.f, hi.f};
}
// async 16B global -> LDS (dest is wave-uniform base + lane*16)
__device__ __forceinline__ void gload_lds16(const void* g, void* l) {
    __builtin_amdgcn_global_load_lds(
        (const __attribute__((address_space(1))) unsigned int*)g,
        (__attribute__((address_space(3))) unsigned int*)l, 16, 0, 0);
}
// Index accessor robust to int32 vs int64 (little-endian, nonneg values < 2^31)
__device__ __forceinline__ int idx_at(const int* p, int e, int is64) {
    return is64 ? p[2 * e] : p[e];
}
// Per-block int64 detection: int64 => odd 32-bit words (high halves) all zero.
__device__ __forceinline__ int block_is64(const int* dst, int nE, int* s_flag) {
    if (threadIdx.x == 0) *s_flag = 0;
    __syncthreads();
    int w = 2 * (int)threadIdx.x + 1;
    if (threadIdx.x < 128 && w < nE && dst[w] != 0) atomicOr(s_flag, 1);
    __syncthreads();
    return !*s_flag;
}

// ---- prep: one kernel, roles by blockIdx (histogram first so the scattered
// atomics overlap the streaming conversion):
// [0, nHistB)   : in-degree histogram, 4 edges/thread (deg pre-zeroed)
// [+nConvH)     : h fp32 -> hB bf16, 8192 elems/block, 8 loads in flight
// [+48)         : 3 weights transposed+converted into Wt
// [+nEmbB)      : emb fp32 -> embB bf16
__global__ __launch_bounds__(256) void prep_k(
    const float* __restrict__ h,
    const float* __restrict__ W0, const float* __restrict__ W1,
    const float* __restrict__ W2, const float* __restrict__ emb,
    const int* __restrict__ dst,
    unsigned short* __restrict__ hB,
    unsigned short* __restrict__ embB, unsigned short* __restrict__ Wt,
    int* __restrict__ deg, int nN, int nEmbEl, int nE) {
    int tid = threadIdx.x;
    int bid = blockIdx.x;
    int nHistB = (nE + 1023) / 1024;
    if (bid < nHistB) {
        __shared__ int s_flag;
        int is64 = block_is64(dst, nE, &s_flag);
        int e0 = bid * 1024 + tid * 4;
        #pragma unroll
        for (int j = 0; j < 4; ++j) {
            int e = e0 + j;
            if (e < nE) atomicAdd(deg + idx_at(dst, e, is64), 1);
        }
        return;
    }
    bid -= nHistB;
    int totalH = nN * DD;
    int nConvH = (totalH + 8191) / 8192;
    if (bid < nConvH) {
        int base0 = bid * 8192;
        if (base0 + 8192 <= totalH) {
            int base = base0 + tid * 8;
            f32x4 x[4][2];
            #pragma unroll
            for (int i = 0; i < 4; ++i) {
                x[i][0] = *(const f32x4*)(h + base + i * 2048);
                x[i][1] = *(const f32x4*)(h + base + i * 2048 + 4);
            }
            #pragma unroll
            for (int i = 0; i < 4; ++i) {
                short8 p;
                #pragma unroll
                for (int j = 0; j < 4; ++j) {
                    p[j]     = (short)f2bf(x[i][0][j]);
                    p[4 + j] = (short)f2bf(x[i][1][j]);
                }
                *(short8*)(hB + base + i * 2048) = p;
            }
        } else {
            #pragma unroll
            for (int i = 0; i < 4; ++i) {
                int b2 = base0 + i * 2048 + tid * 8;
                if (b2 + 8 <= totalH) {
                    f32x4 x0 = *(const f32x4*)(h + b2);
                    f32x4 x1 = *(const f32x4*)(h + b2 + 4);
                    short8 p;
                    #pragma unroll
                    for (int j = 0; j < 4; ++j) {
                        p[j]     = (short)f2bf(x0[j]);
                        p[4 + j] = (short)f2bf(x1[j]);
                    }
                    *(short8*)(hB + b2) = p;
                } else {
                    for (int j = b2; j < totalH && j < b2 + 8; ++j)
                        hB[j] = f2bf(h[j]);
                }
            }
        }
        return;
    }
    bid -= nConvH;
    if (bid < 48) {
        const float* Ws[3] = {W0, W1, W2};
        int w = bid >> 4, chunk = bid & 15;
        unsigned short* T = Wt + w * (DD * DD);
        #pragma unroll
        for (int i = 0; i < 4; ++i) {
            int t = chunk * 1024 + i * 256 + tid;
            int n = t >> 7, k = t & 127;
            T[t] = f2bf(Ws[w][k * DD + n]);
        }
        return;
    }
    bid -= 48;
    // emb role
    int base = bid * 2048 + tid * 8;
    if (base + 8 <= nEmbEl) {
        f32x4 x0 = *(const f32x4*)(emb + base);
        f32x4 x1 = *(const f32x4*)(emb + base + 4);
        short8 p;
        #pragma unroll
        for (int j = 0; j < 4; ++j) {
            p[j]     = (short)f2bf(x0[j]);
            p[4 + j] = (short)f2bf(x1[j]);
        }
        *(short8*)(embB + base) = p;
    } else {
        for (int j = base; j < nEmbEl; ++j) embB[j] = f2bf(emb[j]);
    }
}

// ---- exclusive scan, step 1
__global__ __launch_bounds__(1024) void scan1_k(const int* deg, int* off, int* bsum,
                                                int nN) {
    __shared__ int s[1024];
    int t = threadIdx.x, i = blockIdx.x * 1024 + t;
    int v = (i < nN) ? deg[i] : 0;
    s[t] = v;
    __syncthreads();
    for (int d = 1; d < 1024; d <<= 1) {
        int x = (t >= d) ? s[t - d] : 0;
        __syncthreads();
        s[t] += x;
        __syncthreads();
    }
    if (i < nN) off[i] = s[t] - v;
    if (t == 1023) bsum[blockIdx.x] = s[1023];
}

// ---- steps 2+3 merged; also emits per-bucket (128 nodes) base cursors
__global__ __launch_bounds__(1024) void scan23_k(const int* bsum, int* off,
                                                 int* cursorB, int nN, int nB) {
    __shared__ int s[1024];
    int t = threadIdx.x;
    s[t] = (t < nB) ? bsum[t] : 0;
    __syncthreads();
    for (int d = 1; d < 1024; d <<= 1) {
        int x = (t >= d) ? s[t - d] : 0;
        __syncthreads();
        s[t] += x;
        __syncthreads();
    }
    int base = (blockIdx.x == 0) ? 0 : s[blockIdx.x - 1];
    int i = blockIdx.x * 1024 + t;
    if (i < nN) {
        int o = off[i] + base;
        off[i] = o;
        if ((i & 127) == 0) cursorB[i >> 7] = o;   // bucket run base
    }
}

// ---- sort phase 1: partition edges into coarse buckets (dst>>7) with
// per-(block,bucket) contiguous runs so scattered writes line-merge.
// staged word = src | et<<17 | (dst&127)<<25  (fits: 17+8+7 = 32 bits).
// Requires nBuck <= 2048 (nN <= 262144).
__global__ __launch_bounds__(256) void sort1_k(
    const int* __restrict__ src, const int* __restrict__ dst,
    const int* __restrict__ et, int nE, int nBuck,
    int* __restrict__ cursorB, unsigned int* __restrict__ staging) {
    __shared__ int hist[2048];
    __shared__ int rbase[2048];
    __shared__ unsigned short ranks[SCHUNK];
    __shared__ int s_flag;
    int tid = threadIdx.x;
    int is64 = block_is64(dst, nE, &s_flag);
    for (int i = tid; i < nBuck; i += 256) hist[i] = 0;
    __syncthreads();
    int cbase = blockIdx.x * SCHUNK;
    #pragma unroll
    for (int j = 0; j < SCHUNK / 256; ++j) {
        int e = cbase + j * 256 + tid;
        if (e < nE) {
            int d = idx_at(dst, e, is64);
            ranks[j * 256 + tid] = (unsigned short)atomicAdd(&hist[d >> 7], 1);
        }
    }
    __syncthreads();
    for (int b = tid; b < nBuck; b += 256) {
        int c = hist[b];
        if (c) rbase[b] = atomicAdd(cursorB + b, c);
    }
    __syncthreads();
    #pragma unroll
    for (int j = 0; j < SCHUNK / 256; ++j) {
        int e = cbase + j * 256 + tid;
        if (e < nE) {
            int d = idx_at(dst, e, is64);
            unsigned int wd = (unsigned int)idx_at(src, e, is64) |
                              ((unsigned int)idx_at(et, e, is64) << 17) |
                              ((unsigned int)(d & 127) << 25);
            staging[rbase[d >> 7] + (int)ranks[j * 256 + tid]] = wd;
        }
    }
}

// ---- sort phase 2: one block per bucket; stream the bucket's contiguous
// staging region, scatter to final per-node positions via LDS cursors.
// Writes confined to the block's own small region -> coalesced writeback.
__global__ __launch_bounds__(256) void sort2_k(
    const unsigned int* __restrict__ staging, const int* __restrict__ off,
    int nN, int nE, unsigned int* __restrict__ edges) {
    __shared__ int cur[128];
    int b = blockIdx.x;
    int first = b << 7;
    int tid = threadIdx.x;
    if (tid < 128 && first + tid < nN) cur[tid] = off[first + tid];
    int rStart = off[first];
    int nxt = first + 128;
    int rEnd = (nxt < nN) ? off[nxt] : nE;
    __syncthreads();
    for (int i = rStart + tid; i < rEnd; i += 256) {
        unsigned int wd = staging[i];
        int p = atomicAdd(&cur[wd >> 25], 1);
        edges[p] = wd & 0x1FFFFFFu;
    }
}

// ---- CSR gather, node-per-16-lane-group: 4 nodes per wave, 16 nodes per
// block. Each group walks its node's edge list 2 edges at a time (4 groups x
// 4 row-loads = 16 loads in flight per wave, same as before) and accumulates
// channels lane-locally -- NO cross-lane reduce, no slot waste at avg deg 6.
// lo/hi bf16 unpack into f32x2 accumulators (v_pk_add_f32), epilogue packs
// with v_cvt_pk_bf16_f32 (RNE, same rounding as f2bf). ~2x fewer wave-instrs
// per node than the slot-parallel form (VALU-issue was 49% of 47us).
__global__ __launch_bounds__(256) void gather_k(
    const unsigned short* __restrict__ hB, const unsigned short* __restrict__ embB,
    const unsigned int* __restrict__ edges, const int* __restrict__ off,
    const int* __restrict__ deg, const float* __restrict__ normv,
    char* __restrict__ aggP, int nN) {
    int lane = threadIdx.x & 63;
    int l16 = lane & 15;
    int v = blockIdx.x * 16 + ((threadIdx.x >> 6) << 2) + (lane >> 4);
    if (v >= nN) return;
    int b = off[v], n = deg[v];
    f32x2 a2[4] = {{0.f, 0.f}, {0.f, 0.f}, {0.f, 0.f}, {0.f, 0.f}};
    for (int m = 0; m < n; m += 2) {
        bool e1 = (m + 1) < n;
        unsigned int w0 = edges[b + m];
        unsigned int w1 = e1 ? edges[b + m + 1] : 0u;
        short8 h0 = *(const short8*)(hB + (size_t)(w0 & 0x1FFFFu) * DD + l16 * 8);
        short8 r0 = *(const short8*)(embB + (size_t)(w0 >> 17) * DD + l16 * 8);
        short8 h1, r1;
        if (e1) {
            h1 = *(const short8*)(hB + (size_t)(w1 & 0x1FFFFu) * DD + l16 * 8);
            r1 = *(const short8*)(embB + (size_t)(w1 >> 17) * DD + l16 * 8);
        }
        union { short8 s; u32x4 u; } ch0, cr0;
        ch0.s = h0; cr0.s = r0;
        #pragma unroll
        for (int k = 0; k < 4; ++k) {
            a2[k] += bf2lohi(ch0.u[k]);
            a2[k] += bf2lohi(cr0.u[k]);
        }
        if (e1) {
            union { short8 s; u32x4 u; } ch1, cr1;
            ch1.s = h1; cr1.s = r1;
            #pragma unroll
            for (int k = 0; k < 4; ++k) {
                a2[k] += bf2lohi(ch1.u[k]);
                a2[k] += bf2lohi(cr1.u[k]);
            }
        }
    }
    float nm = normv[v];
    unsigned int pk[4];
    #pragma unroll
    for (int k = 0; k < 4; ++k) {
        float x0 = a2[k][0] * nm, x1 = a2[k][1] * nm;
        asm("v_cvt_pk_bf16_f32 %0, %1, %2" : "=v"(pk[k]) : "v"(x0), "v"(x1));
    }
    i32x4 w;
    w[0] = (int)pk[0]; w[1] = (int)pk[1]; w[2] = (int)pk[2]; w[3] = (int)pk[3];
    *(i32x4*)(aggP + (size_t)v * 512 + l16 * 16) = w;
}

// ---- fused 3-GEMM + epilogue: persistent double-buffered pipeline,
// 32-node tiles, 48KB dynamic LDS -> 2 blocks/CU. While one block drains its
// staging barrier the co-resident block computes (inter-block overlap replaces
// the impossible intra-block one: __syncthreads drains vmcnt(0) including the
// fresh prefetch). Wt fragments hoisted to registers. Swizzle: chunk XOR row.
// deg==0 rows patched exactly by fix_k afterwards.
__global__ __launch_bounds__(256, 2) void fused_k(
    const unsigned short* __restrict__ hB,
    const float* __restrict__ prevh,
    const float* __restrict__ bias,
    const char* __restrict__ aggP,       // = d_out: [0,256) of each 512B slot = agg bf16
    const unsigned short* __restrict__ Wt,
    float* __restrict__ out, int nN, int nTiles) {
    extern __shared__ unsigned short lds[];   // 2 * 12288 u16 = 48KB
    const int lane = threadIdx.x & 63;
    const int wv = threadIdx.x >> 6;
    const int q = lane >> 4, cl = lane & 15;
    const int ncb = wv * 32;
    const int stride = gridDim.x;

    int t = blockIdx.x;
    if (t >= nTiles) return;

    // hoisted Wt fragments (loop-invariant; L2-resident)
    short8 bn[4][2], bl[4][2], bs[4][2];
    #pragma unroll
    for (int ks = 0; ks < 4; ++ks)
        #pragma unroll
        for (int nt = 0; nt < 2; ++nt) {
            int n = (ncb + nt * 16 + cl) * DD + ks * 32 + q * 8;
            bn[ks][nt] = *(const short8*)(Wt + n);
            bl[ks][nt] = *(const short8*)(Wt + DD * DD + n);
            bs[ks][nt] = *(const short8*)(Wt + 2 * DD * DD + n);
        }
    const float b0 = bias[ncb + cl], b1 = bias[ncb + 16 + cl];

    const int r0 = lane >> 4;      // 0..3  (staging row-in-group)
    const int c16 = lane & 15;     // staging chunk

    // ---- prologue: stage tile t into buffer 0
    {
        int node_base = t * 32;
        #pragma unroll
        for (int it = 0; it < 2; ++it) {
            int r = it * 16 + wv * 4 + r0;
            int row = node_base + r; if (row > nN - 1) row = nN - 1;
            int sw = (c16 ^ (r & 15)) << 4;
            char* bptr = (char*)lds + (it * 16 + wv * 4) * 256;
            gload_lds16(aggP + (size_t)row * 512 + sw, bptr);
            gload_lds16((const char*)hB + (size_t)row * 256 + sw, bptr + 8192);
        }
        f32x4 p0[2], p1[2];
        #pragma unroll
        for (int it = 0; it < 2; ++it) {
            int pos = it * 512 + lane * 8;
            int node = node_base + wv * 8 + (pos >> 7);
            if (node > nN - 1) node = nN - 1;
            const float* g = prevh + (size_t)node * DD + (pos & 127);
            p0[it] = *(const f32x4*)g;
            p1[it] = *(const f32x4*)(g + 4);
        }
        #pragma unroll
        for (int it = 0; it < 2; ++it) {
            int pos = it * 512 + lane * 8;
            int r = wv * 8 + (pos >> 7);
            int c = (pos & 127) >> 3;
            short8 p;
            #pragma unroll
            for (int j = 0; j < 4; ++j) {
                p[j]     = (short)f2bf(p0[it][j]);
                p[4 + j] = (short)f2bf(p1[it][j]);
            }
            *(short8*)((char*)lds + 16384 + r * 256 + ((c ^ (r & 15)) << 4)) = p;
        }
    }
    __syncthreads();

    int cur = 0;
    for (;;) {
        int node_base = t * 32;
        int tn = t + stride;
        bool more = (tn < nTiles);

        // ---- prefetch tile tn into buffer cur^1 (issue-early)
        f32x4 p0[2], p1[2];
        if (more) {
            int nb2 = tn * 32;
            char* dbuf = (char*)lds + (cur ^ 1) * 24576;
            #pragma unroll
            for (int it = 0; it < 2; ++it) {
                int r = it * 16 + wv * 4 + r0;
                int row = nb2 + r; if (row > nN - 1) row = nN - 1;
                int sw = (c16 ^ (r & 15)) << 4;
                char* bptr = dbuf + (it * 16 + wv * 4) * 256;
                gload_lds16(aggP + (size_t)row * 512 + sw, bptr);
                gload_lds16((const char*)hB + (size_t)row * 256 + sw, bptr + 8192);
            }
            #pragma unroll
            for (int it = 0; it < 2; ++it) {
                int pos = it * 512 + lane * 8;
                int node = nb2 + wv * 8 + (pos >> 7);
                if (node > nN - 1) node = nN - 1;
                const float* g = prevh + (size_t)node * DD + (pos & 127);
                p0[it] = *(const f32x4*)g;
                p1[it] = *(const f32x4*)(g + 4);
            }
        }

        // ---- compute tile t from buffer cur
        const unsigned short* lA = lds + cur * 12288;
        const unsigned short* lH = lA + 4096;
        const unsigned short* lP = lA + 8192;

        f32x4 accM[2][2], accG[2][2];
        #pragma unroll
        for (int mt = 0; mt < 2; ++mt)
            #pragma unroll
            for (int nt = 0; nt < 2; ++nt) {
                accM[mt][nt] = (f32x4){0.f, 0.f, 0.f, 0.f};
                accG[mt][nt] = (f32x4){0.f, 0.f, 0.f, 0.f};
            }
        #pragma unroll
        for (int ks = 0; ks < 4; ++ks) {
            int swz = ((ks * 4 + q) ^ cl) << 3;
            #pragma unroll
            for (int mt = 0; mt < 2; ++mt) {
                int off = (mt * 16 + cl) * 128 + swz;
                short8 aA = *(const short8*)(lA + off);
                short8 aH = *(const short8*)(lH + off);
                short8 aP = *(const short8*)(lP + off);
                #pragma unroll
                for (int nt = 0; nt < 2; ++nt) {
                    accM[mt][nt] = __builtin_amdgcn_mfma_f32_16x16x32_bf16(
                        aA, bn[ks][nt], accM[mt][nt], 0, 0, 0);
                    accM[mt][nt] = __builtin_amdgcn_mfma_f32_16x16x32_bf16(
                        aH, bl[ks][nt], accM[mt][nt], 0, 0, 0);
                    accG[mt][nt] = __builtin_amdgcn_mfma_f32_16x16x32_bf16(
                        aP, bs[ks][nt], accG[mt][nt], 0, 0, 0);
                }
            }
        }

        // ---- epilogue: C/D layout col = lane&15, row = quad*4 + reg
        #pragma unroll
        for (int mt = 0; mt < 2; ++mt) {
            #pragma unroll
            for (int r = 0; r < 4; ++r) {
                int nrow = mt * 16 + q * 4 + r;
                int node = node_base + nrow;
                if (node >= nN) continue;
                #pragma unroll
                for (int nt = 0; nt < 2; ++nt) {
                    int col = ncb + nt * 16 + cl;
                    float pv = bfu(lP[nrow * 128 +
                                      ((((col >> 3) ^ (nrow & 15)) << 3) | (col & 7))]);
                    float sg = 1.0f / (1.0f + __expf(-(accG[mt][nt][r] +
                                                       (nt ? b1 : b0))));
                    float o  = sg * accM[mt][nt][r] + (1.0f - sg) * pv;
                    out[(size_t)node * DD + col] = (o > 0.f ? o : 0.f);
                }
            }
        }

        // ---- write-late: prevh of tile tn -> PB slab of buffer cur^1
        if (more) {
            char* dbuf = (char*)lds + (cur ^ 1) * 24576;
            #pragma unroll
            for (int it = 0; it < 2; ++it) {
                int pos = it * 512 + lane * 8;
                int r = wv * 8 + (pos >> 7);
                int c = (pos & 127) >> 3;
                short8 p;
                #pragma unroll
                for (int j = 0; j < 4; ++j) {
                    p[j]     = (short)f2bf(p0[it][j]);
                    p[4 + j] = (short)f2bf(p1[it][j]);
                }
                *(short8*)(dbuf + 16384 + r * 256 + ((c ^ (r & 15)) << 4)) = p;
            }
        }
        __syncthreads();
        if (!more) break;
        cur ^= 1;
        t = tn;
    }
}

// ---- patch deg==0 nodes exactly (fp32)
__global__ __launch_bounds__(256) void fix_k(
    const float* __restrict__ h, const float* __restrict__ prevh,
    const float* __restrict__ bias, const float* __restrict__ We,
    const float* __restrict__ Wsk, const int* __restrict__ deg,
    float* __restrict__ out, int nN, int chunk) {
    __shared__ int list[256];
    __shared__ int cnt;
    __shared__ float hrow[DD], prow[DD], res[2][DD];
    int tid = threadIdx.x;
    int base = blockIdx.x * chunk;
    for (int c = base; c < base + chunk && c < nN; c += 256) {
        if (tid == 0) cnt = 0;
        __syncthreads();
        int v = c + tid;
        if (v < nN && v < base + chunk && deg[v] == 0)
            list[atomicAdd(&cnt, 1)] = v;
        __syncthreads();
        int m = cnt;
        for (int i = 0; i < m; ++i) {
            int node = list[i];
            if (tid < DD) hrow[tid] = h[(size_t)node * DD + tid];
            else prow[tid - DD] = prevh[(size_t)node * DD + tid - DD];
            __syncthreads();
            int col = tid & (DD - 1);
            int half = tid >> 7;
            const float* W = half ? Wsk : We;
            const float* x = half ? prow : hrow;
            float s = 0.f;
            for (int k = 0; k < DD; ++k) s += x[k] * W[k * DD + col];
            res[half][col] = s;
            __syncthreads();
            if (tid < DD) {
                float sg = 1.0f / (1.0f + __expf(-(res[1][col] + bias[col])));
                float o  = sg * res[0][col] + (1.0f - sg) * prow[col];
                out[(size_t)node * DD + col] = (o > 0.f ? o : 0.f);
            }
            __syncthreads();
        }
        __syncthreads();
    }
}

extern "C" void kernel_launch(void* const* d_in, const int* in_sizes, int n_in,
                              void* d_out, int out_size, void* d_ws, size_t ws_size,
                              hipStream_t stream) {
    const float* h     = (const float*)d_in[0];
    const float* prevh = (const float*)d_in[1];
    const float* emb   = (const float*)d_in[2];
    const float* normv = (const float*)d_in[3];
    const float* Wn    = (const float*)d_in[4];
    const float* Wl    = (const float*)d_in[5];
    const float* We    = (const float*)d_in[6];
    const float* Wsk   = (const float*)d_in[7];
    const float* bias  = (const float*)d_in[8];
    const int* src   = (const int*)d_in[9];
    const int* dst   = (const int*)d_in[10];
    const int* etype = (const int*)d_in[11];

    int nN = in_sizes[3];       // norm is [N,1]
    int nE = in_sizes[9];
    int nEmbEl = in_sizes[2];   // NUM_RELS * 128

    // ws: Wt 96KB (Wn,Wl,Wsk) | embB | deg off cursorB bsum | edges u32 |
    //     staging u32 | hB    => ~32 MB
    char* w = (char*)d_ws;
    size_t o = 0;
    unsigned short* Wt = (unsigned short*)(w + o);  o += 3 * DD * DD * 2;
    unsigned short* embB = (unsigned short*)(w + o); o += ((size_t)nEmbEl * 2 + 255) & ~(size_t)255;
    int* deg     = (int*)(w + o);  o += ((size_t)nN * 4 + 15) & ~(size_t)15;
    int* offA    = (int*)(w + o);  o += ((size_t)nN * 4 + 15) & ~(size_t)15;
    int* cursorB = (int*)(w + o);  o += 8192;
    int* bsum    = (int*)(w + o);  o += 4096;
    unsigned int* edges   = (unsigned int*)(w + o); o += ((size_t)nE * 4 + 15) & ~(size_t)15;
    unsigned int* staging = (unsigned int*)(w + o); o += ((size_t)nE * 4 + 15) & ~(size_t)15;
    unsigned short* hB = (unsigned short*)(w + o);

    int totalH = nN * DD;
    int nConvH = (totalH + 8191) / 8192;
    int nEmbB  = (nEmbEl + 2047) / 2048;
    int nHistB = (nE + 1023) / 1024;
    int nB = (nN + 1023) / 1024;
    int nBuck = (nN + 127) / 128;          // <= 2048 for nN <= 262144
    int nTiles = (nN + 31) / 32;
    int fgrid2 = nTiles < 512 ? nTiles : 512;

    hipMemsetAsync(deg, 0, (size_t)nN * sizeof(int), stream);
    prep_k<<<nHistB + nConvH + 48 + nEmbB, 256, 0, stream>>>(
        h, Wn, Wl, Wsk, emb, dst, hB, embB, Wt, deg, nN, nEmbEl, nE);
    scan1_k<<<nB, 1024, 0, stream>>>(deg, offA, bsum, nN);
    scan23_k<<<nB, 1024, 0, stream>>>(bsum, offA, cursorB, nN, nB);
    sort1_k<<<(nE + SCHUNK - 1) / SCHUNK, 256, 0, stream>>>(
        src, dst, etype, nE, nBuck, cursorB, staging);
    sort2_k<<<nBuck, 256, 0, stream>>>(staging, offA, nN, nE, edges);
    gather_k<<<(nN + 15) / 16, 256, 0, stream>>>(hB, embB, edges, offA, deg, normv,
                                                 (char*)d_out, nN);
    fused_k<<<fgrid2, 256, 49152, stream>>>(hB, prevh, bias, (const char*)d_out,
                                            Wt, (float*)d_out, nN, nTiles);
    int fgrid = 256;
    int chunk = ((nN + fgrid * 256 - 1) / (fgrid * 256)) * 256;
    fix_k<<<fgrid, 256, 0, stream>>>(h, prevh, bias, We, Wsk, deg, (float*)d_out,
                                     nN, chunk);
    (void)ws_size; (void)n_in; (void)out_size;
}